// Round 5
// baseline (266.458 us; speedup 1.0000x reference)
//
#include <hip/hip_runtime.h>

#define NN 50000
#define NE 800000
#define NB4 12500      // NN/4 gather batches (4 nodes/wave, 16 lanes/node)
#define NT 3125        // NN/16 mfma tiles
#define SCB 49         // ceil(NN/1024) scan blocks
#define NBK 128        // coarse buckets
#define BNODE 391      // nodes per bucket (391*128 = 50048 >= NN)
#define BCAP 7680      // bucket capacity (mean 6250, +18 sigma)
#define SCAP 56        // per-block LDS stage capacity per bucket

typedef __attribute__((ext_vector_type(8))) short short8x;
typedef __attribute__((ext_vector_type(4))) float f32x4;

// ws layout (float-index offsets)
#define OFF_CNT   0LL                 // NN ints (counts)
#define OFF_ROW   ((long long)NN)     // NN+1 ints (row_ptr)
#define OFF_RECS  (3LL*NN + 16)       // NE int2
#define OFF_FLAGS (35LL*NN + 16)      // ints
#define OFF_BS    (35LL*NN + 32)      // 64 ints
#define OFF_BO    (35LL*NN + 96)      // 64 ints
#define OFF_PK    (35LL*NN + 160)     // 15360 ushorts (16B-aligned)
#define OFF_FB1S  (35LL*NN + 7840)    // 64 f32
#define OFF_FB2S  (35LL*NN + 7904)    // 32 f32
#define OFF_F1    (36LL*NN)           // NN*160 bf16  (binbuf aliases this region)
#define OFF_F2    (116LL*NN)          // NN*96 bf16
#define OFF_Y2B   (164LL*NN)          // NN*32 bf16
#define OFF_S2    (180LL*NN)          // NN*32 f32
#define OFF_BCUR  (212LL*NN)          // 128 ints

__device__ __forceinline__ float ldf(const void* p, long long i, int bf16) {
  if (bf16) {
    unsigned short u = ((const unsigned short*)p)[i];
    return __uint_as_float(((unsigned)u) << 16);
  }
  return ((const float*)p)[i];
}
__device__ __forceinline__ unsigned short f2bf(float f) {
  unsigned u = __float_as_uint(f);
  unsigned r = (u + 0x7fffu + ((u >> 16) & 1u)) >> 16;
  return (unsigned short)r;
}
__device__ __forceinline__ unsigned pk2(float lo, float hi) {
  return (unsigned)f2bf(lo) | ((unsigned)f2bf(hi) << 16);
}
__device__ __forceinline__ int ldidx(const void* p, long long i, int i64) {
  return i64 ? (int)((const long long*)p)[i] : ((const int*)p)[i];
}
__device__ __forceinline__ float bflo(unsigned u) { return __uint_as_float(u << 16); }
__device__ __forceinline__ float bfhi(unsigned u) { return __uint_as_float(u & 0xffff0000u); }

// ---------------- detect dtypes ----------------
__global__ void k_detect(const void* ei, const void* x, int* flags) {
  int lane = threadIdx.x & 63;
  const int* p = (const int*)ei;
  int any = 0;
  for (int i = lane; i < 256; i += 64) any |= p[2 * i + 1];
  unsigned long long anyb = __ballot(any != 0);
  const unsigned short* q = (const unsigned short*)x;
  int cnt = 0;
  for (int i = lane; i < 256; i += 64) {
    unsigned short w = q[2 * i];
    int e = (w >> 7) & 0xff;
    if (w == 0 || (e >= 110 && e <= 140)) cnt++;
  }
  for (int m = 1; m < 64; m <<= 1) cnt += __shfl_xor(cnt, m, 64);
  if (lane == 0) {
    flags[0] = (anyb == 0ull) ? 1 : 0;
    flags[1] = (cnt >= 192) ? 1 : 0;
  }
}

// ---------------- pack BN-folded weights into MFMA B-fragment order ----------------
__global__ __launch_bounds__(256) void k_prep(
    const void* __restrict__ W1_msg, const void* __restrict__ b1_msg,
    const void* __restrict__ W1_self, const void* __restrict__ b1_self,
    const void* __restrict__ gamma, const void* __restrict__ beta,
    const void* __restrict__ mean, const void* __restrict__ var,
    const void* __restrict__ W2_msg, const void* __restrict__ b2_msg,
    const void* __restrict__ W2_self, const void* __restrict__ b2_self,
    const int* __restrict__ flags, unsigned short* __restrict__ PK,
    float* __restrict__ fb1s, float* __restrict__ fb2s) {
  int bf = flags[1];
  int t0 = blockIdx.x * 256 + threadIdx.x;
  int stride = gridDim.x * 256;
  for (int i = t0; i < 10240; i += stride) {
    int j = i & 7, L = (i >> 3) & 63, t = (i >> 9) & 3, c = i >> 11;
    int k = c * 32 + ((L >> 4) << 3) + j;
    int col = t * 16 + (L & 15);
    float sc = ldf(gamma, col, bf) * rsqrtf(ldf(var, col, bf) + 1e-5f);
    float v;
    if (k < 64) v = ldf(W1_msg, k * 64 + col, bf) * sc;
    else if (k < 128) v = ldf(W1_self, (k - 64) * 64 + col, bf) * sc;
    else if (k < 144) v = ldf(W1_msg, (64 + k - 128) * 64 + col, bf) * sc;
    else if (k == 144) v = ldf(b1_msg, col, bf) * sc;
    else v = 0.0f;
    PK[i] = f2bf(v);
  }
  for (int i = t0; i < 2048; i += stride) {
    int j = i & 7, L = (i >> 3) & 63, t = (i >> 9) & 1, c = i >> 10;
    int k = c * 32 + ((L >> 4) << 3) + j;
    int col = t * 16 + (L & 15);
    PK[10240 + i] = f2bf(ldf(W2_msg, k * 32 + col, bf));
  }
  for (int i = t0; i < 3072; i += stride) {
    int j = i & 7, L = (i >> 3) & 63, t = (i >> 9) & 1, c = i >> 10;
    int k = c * 32 + ((L >> 4) << 3) + j;
    int col = t * 16 + (L & 15);
    float v;
    if (k < 64) v = ldf(W2_self, k * 32 + col, bf);
    else if (k < 80) v = ldf(W2_msg, k * 32 + col, bf);
    else if (k == 80) v = ldf(b2_msg, col, bf);
    else v = 0.0f;
    PK[12288 + i] = f2bf(v);
  }
  for (int i = t0; i < 64; i += stride) {
    float sc = ldf(gamma, i, bf) * rsqrtf(ldf(var, i, bf) + 1e-5f);
    fb1s[i] = ldf(b1_self, i, bf) * sc + ldf(beta, i, bf) - ldf(mean, i, bf) * sc;
  }
  for (int i = t0; i < 32; i += stride) fb2s[i] = ldf(b2_self, i, bf);
}

// ---------------- phase 1: LDS-staged binning by dst/391 ----------------
__global__ __launch_bounds__(256) void k_bin(const void* __restrict__ ei,
                                             const int* __restrict__ flags,
                                             int* __restrict__ bcur,
                                             int2* __restrict__ binbuf) {
  __shared__ int2 stage[NBK][SCAP];  // 57.3 KB
  __shared__ int scnt[NBK];
  __shared__ int gbase[NBK];
  int tid = threadIdx.x;
  for (int i = tid; i < NBK; i += 256) scnt[i] = 0;
  __syncthreads();
  int i64 = flags[0];
  for (long long e0 = (long long)blockIdx.x * 256; e0 < NE;
       e0 += (long long)gridDim.x * 256) {
    long long e = e0 + tid;
    if (e < NE) {
      int src = ldidx(ei, e, i64);
      int dst = ldidx(ei, NE + e, i64);
      int b = dst / BNODE;
      int dl = dst - b * BNODE;
      int2 ent = make_int2(src | (dl << 16), (int)e);
      int pos = atomicAdd(&scnt[b], 1);
      if (pos < SCAP) {
        stage[b][pos] = ent;
      } else {  // rare overflow: direct global placement
        int gp = atomicAdd(&bcur[b], 1);
        binbuf[(long long)b * BCAP + gp] = ent;
      }
    }
  }
  __syncthreads();
  if (tid < NBK) {
    int cb = scnt[tid] < SCAP ? scnt[tid] : SCAP;
    gbase[tid] = atomicAdd(&bcur[tid], cb);
  }
  __syncthreads();
  for (int b = 0; b < NBK; ++b) {
    int cb = scnt[b] < SCAP ? scnt[b] : SCAP;
    for (int i = tid; i < cb; i += 256)
      binbuf[(long long)b * BCAP + gbase[b] + i] = stage[b][i];
  }
}

// ---------------- phase 1.5: per-bucket LDS histogram -> counts ----------------
__global__ __launch_bounds__(256) void k_bhist(const int* __restrict__ bcur,
                                               const int2* __restrict__ binbuf,
                                               int* __restrict__ counts) {
  __shared__ int lh[BNODE];
  int b = blockIdx.x;
  int tid = threadIdx.x;
  for (int i = tid; i < BNODE; i += 256) lh[i] = 0;
  __syncthreads();
  int cnt = bcur[b];
  for (int i = tid; i < cnt; i += 256) {
    int dl = (binbuf[(long long)b * BCAP + i].x >> 16) & 0x3FF;
    atomicAdd(&lh[dl], 1);
  }
  __syncthreads();
  int base = b * BNODE;
  int nn = NN - base < BNODE ? NN - base : BNODE;
  for (int i = tid; i < nn; i += 256) counts[base + i] = lh[i];
}

// ---------------- scan (3 phases) ----------------
__global__ __launch_bounds__(1024) void k_scanA(const int* __restrict__ counts,
                                                int* __restrict__ bs) {
  __shared__ int sd[1024];
  int t = threadIdx.x;
  int i = blockIdx.x * 1024 + t;
  sd[t] = (i < NN) ? counts[i] : 0;
  __syncthreads();
  for (int off = 512; off > 0; off >>= 1) {
    if (t < off) sd[t] += sd[t + off];
    __syncthreads();
  }
  if (t == 0) bs[blockIdx.x] = sd[0];
}

__global__ void k_scanB(const int* __restrict__ bs, int* __restrict__ bo) {
  int lane = threadIdx.x & 63;
  int v = (lane < SCB) ? bs[lane] : 0;
  int orig = v;
  for (int off = 1; off < 64; off <<= 1) {
    int u = __shfl_up(v, off, 64);
    if (lane >= off) v += u;
  }
  if (lane < SCB) bo[lane] = v - orig;
}

__global__ __launch_bounds__(1024) void k_scanC(const int* __restrict__ counts,
                                                const int* __restrict__ bo,
                                                int* __restrict__ row_ptr) {
  __shared__ int sd[1024];
  int t = threadIdx.x;
  int i = blockIdx.x * 1024 + t;
  int v = (i < NN) ? counts[i] : 0;
  sd[t] = v;
  __syncthreads();
  for (int off = 1; off < 1024; off <<= 1) {
    int u = (t >= off) ? sd[t - off] : 0;
    __syncthreads();
    sd[t] += u;
    __syncthreads();
  }
  int excl = sd[t] - v + bo[blockIdx.x];
  if (i < NN) row_ptr[i] = excl;
  if (i == NN - 1) row_ptr[NN] = excl + v;
}

// ---------------- phase 2: per-bucket LDS placement -> recs (coalesced) ----------------
__global__ __launch_bounds__(256) void k_place(const int* __restrict__ bcur,
                                               const int2* __restrict__ binbuf,
                                               const int* __restrict__ row_ptr,
                                               int2* __restrict__ recs) {
  __shared__ int2 outb[BCAP];  // 60 KB
  __shared__ int lcur[BNODE];
  int b = blockIdx.x;
  int tid = threadIdx.x;
  int base = b * BNODE;
  int nn = NN - base < BNODE ? NN - base : BNODE;
  int rbase = row_ptr[base];
  for (int i = tid; i < nn; i += 256) lcur[i] = row_ptr[base + i] - rbase;
  __syncthreads();
  int cnt = bcur[b];
  for (int i = tid; i < cnt; i += 256) {
    int2 ent = binbuf[(long long)b * BCAP + i];
    int dl = (ent.x >> 16) & 0x3FF;
    int p = atomicAdd(&lcur[dl], 1);
    outb[p] = make_int2(ent.x & 0xFFFF, ent.y);
  }
  __syncthreads();
  for (int i = tid; i < cnt; i += 256) recs[rbase + i] = outb[i];
}

// ---------------- gather 1: 16 lanes/node (4 nodes/wave), unroll-8 ----------------
// natural node order (degree-perm regressed in r3/r4); no NT/prefetch (regressed in r1)
__global__ __launch_bounds__(256) void k_gather1(
    const void* __restrict__ x, const void* __restrict__ ea,
    const int* __restrict__ row_ptr, const int2* __restrict__ recs,
    const int* __restrict__ flags, unsigned short* __restrict__ F1,
    unsigned short* __restrict__ F2) {
  int lane = threadIdx.x & 63;
  int g = lane >> 4, c = lane & 15;
  int bf = flags[1];
  long long wid = ((long long)blockIdx.x * blockDim.x + threadIdx.x) >> 6;
  long long nw = ((long long)gridDim.x * blockDim.x) >> 6;
  for (long long b = wid; b < NB4; b += nw) {
    int n = (int)(b * 4 + g);
    int beg = row_ptr[n];
    int deg = row_ptr[n + 1] - beg;
    float a0 = 0.f, a1 = 0.f, a2 = 0.f, a3 = 0.f;  // x channels 4c..4c+3
    float e0 = 0.f, e1 = 0.f;                       // ea channels 2c, 2c+1 (c<8)
    uint2 xw;
    if (bf) {
      const unsigned short* xs = (const unsigned short*)x;
      const unsigned short* es = (const unsigned short*)ea;
      int t = 0;
      for (; t + 8 <= deg; t += 8) {
        int2 r0 = recs[beg + t + 0];
        int2 r1 = recs[beg + t + 1];
        int2 r2 = recs[beg + t + 2];
        int2 r3 = recs[beg + t + 3];
        int2 r4 = recs[beg + t + 4];
        int2 r5 = recs[beg + t + 5];
        int2 r6 = recs[beg + t + 6];
        int2 r7 = recs[beg + t + 7];
        uint2 w0 = *((const uint2*)(xs + ((long long)r0.x << 6)) + c);
        uint2 w1 = *((const uint2*)(xs + ((long long)r1.x << 6)) + c);
        uint2 w2 = *((const uint2*)(xs + ((long long)r2.x << 6)) + c);
        uint2 w3 = *((const uint2*)(xs + ((long long)r3.x << 6)) + c);
        uint2 w4 = *((const uint2*)(xs + ((long long)r4.x << 6)) + c);
        uint2 w5 = *((const uint2*)(xs + ((long long)r5.x << 6)) + c);
        uint2 w6 = *((const uint2*)(xs + ((long long)r6.x << 6)) + c);
        uint2 w7 = *((const uint2*)(xs + ((long long)r7.x << 6)) + c);
        a0 += bflo(w0.x) + bflo(w1.x) + bflo(w2.x) + bflo(w3.x) +
              bflo(w4.x) + bflo(w5.x) + bflo(w6.x) + bflo(w7.x);
        a1 += bfhi(w0.x) + bfhi(w1.x) + bfhi(w2.x) + bfhi(w3.x) +
              bfhi(w4.x) + bfhi(w5.x) + bfhi(w6.x) + bfhi(w7.x);
        a2 += bflo(w0.y) + bflo(w1.y) + bflo(w2.y) + bflo(w3.y) +
              bflo(w4.y) + bflo(w5.y) + bflo(w6.y) + bflo(w7.y);
        a3 += bfhi(w0.y) + bfhi(w1.y) + bfhi(w2.y) + bfhi(w3.y) +
              bfhi(w4.y) + bfhi(w5.y) + bfhi(w6.y) + bfhi(w7.y);
        if (c < 8) {
          unsigned q0 = *((const unsigned*)(es + ((long long)r0.y << 4)) + c);
          unsigned q1 = *((const unsigned*)(es + ((long long)r1.y << 4)) + c);
          unsigned q2 = *((const unsigned*)(es + ((long long)r2.y << 4)) + c);
          unsigned q3 = *((const unsigned*)(es + ((long long)r3.y << 4)) + c);
          unsigned q4 = *((const unsigned*)(es + ((long long)r4.y << 4)) + c);
          unsigned q5 = *((const unsigned*)(es + ((long long)r5.y << 4)) + c);
          unsigned q6 = *((const unsigned*)(es + ((long long)r6.y << 4)) + c);
          unsigned q7 = *((const unsigned*)(es + ((long long)r7.y << 4)) + c);
          e0 += bflo(q0) + bflo(q1) + bflo(q2) + bflo(q3) +
                bflo(q4) + bflo(q5) + bflo(q6) + bflo(q7);
          e1 += bfhi(q0) + bfhi(q1) + bfhi(q2) + bfhi(q3) +
                bfhi(q4) + bfhi(q5) + bfhi(q6) + bfhi(q7);
        }
      }
      for (; t + 4 <= deg; t += 4) {
        int2 r0 = recs[beg + t + 0];
        int2 r1 = recs[beg + t + 1];
        int2 r2 = recs[beg + t + 2];
        int2 r3 = recs[beg + t + 3];
        uint2 w0 = *((const uint2*)(xs + ((long long)r0.x << 6)) + c);
        uint2 w1 = *((const uint2*)(xs + ((long long)r1.x << 6)) + c);
        uint2 w2 = *((const uint2*)(xs + ((long long)r2.x << 6)) + c);
        uint2 w3 = *((const uint2*)(xs + ((long long)r3.x << 6)) + c);
        a0 += bflo(w0.x) + bflo(w1.x) + bflo(w2.x) + bflo(w3.x);
        a1 += bfhi(w0.x) + bfhi(w1.x) + bfhi(w2.x) + bfhi(w3.x);
        a2 += bflo(w0.y) + bflo(w1.y) + bflo(w2.y) + bflo(w3.y);
        a3 += bfhi(w0.y) + bfhi(w1.y) + bfhi(w2.y) + bfhi(w3.y);
        if (c < 8) {
          unsigned q0 = *((const unsigned*)(es + ((long long)r0.y << 4)) + c);
          unsigned q1 = *((const unsigned*)(es + ((long long)r1.y << 4)) + c);
          unsigned q2 = *((const unsigned*)(es + ((long long)r2.y << 4)) + c);
          unsigned q3 = *((const unsigned*)(es + ((long long)r3.y << 4)) + c);
          e0 += bflo(q0) + bflo(q1) + bflo(q2) + bflo(q3);
          e1 += bfhi(q0) + bfhi(q1) + bfhi(q2) + bfhi(q3);
        }
      }
      for (; t < deg; ++t) {
        int2 r = recs[beg + t];
        uint2 w = *((const uint2*)(xs + ((long long)r.x << 6)) + c);
        a0 += bflo(w.x); a1 += bfhi(w.x);
        a2 += bflo(w.y); a3 += bfhi(w.y);
        if (c < 8) {
          unsigned q = *((const unsigned*)(es + ((long long)r.y << 4)) + c);
          e0 += bflo(q); e1 += bfhi(q);
        }
      }
      xw = *((const uint2*)(xs + ((long long)n << 6)) + c);
    } else {
      const float* xf = (const float*)x;
      const float* ef = (const float*)ea;
      for (int t = 0; t < deg; ++t) {
        int2 r = recs[beg + t];
        float4 w = *((const float4*)(xf + ((long long)r.x << 6)) + c);
        a0 += w.x; a1 += w.y; a2 += w.z; a3 += w.w;
        if (c < 8) {
          float2 q = *((const float2*)(ef + ((long long)r.y << 4)) + c);
          e0 += q.x; e1 += q.y;
        }
      }
      float4 p = *((const float4*)(xf + ((long long)n << 6)) + c);
      xw = make_uint2(pk2(p.x, p.y), pk2(p.z, p.w));
    }
    unsigned short* f1 = F1 + (long long)n * 160;
    unsigned short* f2 = F2 + (long long)n * 96;
    *((uint2*)f1 + c) = make_uint2(pk2(a0, a1), pk2(a2, a3));
    *((uint2*)(f1 + 64) + c) = xw;
    if (c < 8) {
      unsigned sp = pk2(e0, e1);
      ((unsigned*)(f1 + 128))[c] = sp;
      ((unsigned*)(f2 + 64))[c] = sp;
    }
    if (c == 8) {
      unsigned d = (unsigned)f2bf((float)deg);
      *((uint2*)(f1 + 144)) = make_uint2(d, 0u);
      *((uint2*)(f2 + 80)) = make_uint2(d, 0u);
    }
    if (c == 9) {
      *((uint2*)(f1 + 148)) = make_uint2(0u, 0u);
      *((uint2*)(f2 + 84)) = make_uint2(0u, 0u);
    }
    if (c == 10) {
      *((uint2*)(f1 + 152)) = make_uint2(0u, 0u);
      *((uint2*)(f2 + 88)) = make_uint2(0u, 0u);
    }
    if (c == 11) {
      *((uint2*)(f1 + 156)) = make_uint2(0u, 0u);
      *((uint2*)(f2 + 92)) = make_uint2(0u, 0u);
    }
  }
}

// ---------------- gemm 1 (MFMA): F1@B1 + bias -> ReLU -> F2[0..64) ; fused Y2 = h@BY ----------------
__global__ __launch_bounds__(256) void k_gemm1(
    const unsigned short* __restrict__ F1, const unsigned short* __restrict__ PK,
    const float* __restrict__ fb1s, unsigned short* __restrict__ F2,
    unsigned short* __restrict__ Y2B) {
  // per-wave LDS staging for the h-tile transpose (stride 72 shorts = conflict-light)
  __shared__ unsigned short hsh[4][16 * 72];
  int lane = threadIdx.x & 63;
  int wv = threadIdx.x >> 6;
  int m = lane & 15, quad = lane >> 4;
  unsigned short* hs = hsh[wv];
  short8x Bf[20];
#pragma unroll
  for (int s = 0; s < 20; ++s) Bf[s] = *(const short8x*)(PK + (s * 64 + lane) * 8);
  short8x By[4];
#pragma unroll
  for (int s = 0; s < 4; ++s) By[s] = *(const short8x*)(PK + 10240 + (s * 64 + lane) * 8);
  long long gw = (long long)blockIdx.x * 4 + wv;
  long long nw = (long long)gridDim.x * 4;
  for (long long tile = gw; tile < NT; tile += nw) {
    long long n0 = tile * 16;
    const unsigned short* f1 = F1 + (n0 + m) * 160 + quad * 8;
    short8x A[5];
#pragma unroll
    for (int cc = 0; cc < 5; ++cc) A[cc] = *(const short8x*)(f1 + cc * 32);
    f32x4 acc[4];
#pragma unroll
    for (int t = 0; t < 4; ++t) {
      float b = fb1s[t * 16 + m];
      acc[t] = (f32x4){b, b, b, b};
    }
#pragma unroll
    for (int cc = 0; cc < 5; ++cc) {
#pragma unroll
      for (int t = 0; t < 4; ++t)
        acc[t] = __builtin_amdgcn_mfma_f32_16x16x32_bf16(A[cc], Bf[cc * 4 + t], acc[t], 0, 0, 0);
    }
    // write h to F2 (plain, stays in L2 for gemm2) and stage bf16-rounded h in LDS
#pragma unroll
    for (int t = 0; t < 4; ++t) {
#pragma unroll
      for (int i = 0; i < 4; ++i) {
        float h = fmaxf(acc[t][i], 0.0f);
        unsigned short us = f2bf(h);
        F2[(n0 + quad * 4 + i) * 96 + t * 16 + m] = us;
        hs[(quad * 4 + i) * 72 + t * 16 + m] = us;
      }
    }
    __builtin_amdgcn_sched_barrier(0);  // keep ds_reads after ds_writes (wave-synchronous)
    f32x4 yacc[2];
    yacc[0] = (f32x4){0.f, 0.f, 0.f, 0.f};
    yacc[1] = (f32x4){0.f, 0.f, 0.f, 0.f};
#pragma unroll
    for (int cc = 0; cc < 2; ++cc) {
      short8x Ah = *(const short8x*)(hs + m * 72 + cc * 32 + quad * 8);
#pragma unroll
      for (int t = 0; t < 2; ++t)
        yacc[t] = __builtin_amdgcn_mfma_f32_16x16x32_bf16(Ah, By[cc * 2 + t], yacc[t], 0, 0, 0);
    }
#pragma unroll
    for (int t = 0; t < 2; ++t) {
#pragma unroll
      for (int i = 0; i < 4; ++i)
        Y2B[(n0 + quad * 4 + i) * 32 + t * 16 + m] = f2bf(yacc[t][i]);
    }
    __builtin_amdgcn_sched_barrier(0);
  }
}

// ---------------- gather 2: 16 lanes/node (4 nodes/wave), unroll-8 ----------------
__global__ __launch_bounds__(256) void k_gather2(
    const unsigned short* __restrict__ Y2B, const int* __restrict__ row_ptr,
    const int2* __restrict__ recs, float* __restrict__ S2) {
  int lane = threadIdx.x & 63;
  int g = lane >> 4, c = lane & 15;
  long long wid = ((long long)blockIdx.x * blockDim.x + threadIdx.x) >> 6;
  long long nw = ((long long)gridDim.x * blockDim.x) >> 6;
  for (long long b = wid; b < NB4; b += nw) {
    int n = (int)(b * 4 + g);
    int beg = row_ptr[n];
    int deg = row_ptr[n + 1] - beg;
    float s0 = 0.f, s1 = 0.f;  // channels 2c, 2c+1
    int t = 0;
    for (; t + 8 <= deg; t += 8) {
      int2 r0 = recs[beg + t + 0];
      int2 r1 = recs[beg + t + 1];
      int2 r2 = recs[beg + t + 2];
      int2 r3 = recs[beg + t + 3];
      int2 r4 = recs[beg + t + 4];
      int2 r5 = recs[beg + t + 5];
      int2 r6 = recs[beg + t + 6];
      int2 r7 = recs[beg + t + 7];
      unsigned q0 = *((const unsigned*)(Y2B + (long long)r0.x * 32) + c);
      unsigned q1 = *((const unsigned*)(Y2B + (long long)r1.x * 32) + c);
      unsigned q2 = *((const unsigned*)(Y2B + (long long)r2.x * 32) + c);
      unsigned q3 = *((const unsigned*)(Y2B + (long long)r3.x * 32) + c);
      unsigned q4 = *((const unsigned*)(Y2B + (long long)r4.x * 32) + c);
      unsigned q5 = *((const unsigned*)(Y2B + (long long)r5.x * 32) + c);
      unsigned q6 = *((const unsigned*)(Y2B + (long long)r6.x * 32) + c);
      unsigned q7 = *((const unsigned*)(Y2B + (long long)r7.x * 32) + c);
      s0 += bflo(q0) + bflo(q1) + bflo(q2) + bflo(q3) +
            bflo(q4) + bflo(q5) + bflo(q6) + bflo(q7);
      s1 += bfhi(q0) + bfhi(q1) + bfhi(q2) + bfhi(q3) +
            bfhi(q4) + bfhi(q5) + bfhi(q6) + bfhi(q7);
    }
    for (; t + 4 <= deg; t += 4) {
      int2 r0 = recs[beg + t + 0];
      int2 r1 = recs[beg + t + 1];
      int2 r2 = recs[beg + t + 2];
      int2 r3 = recs[beg + t + 3];
      unsigned q0 = *((const unsigned*)(Y2B + (long long)r0.x * 32) + c);
      unsigned q1 = *((const unsigned*)(Y2B + (long long)r1.x * 32) + c);
      unsigned q2 = *((const unsigned*)(Y2B + (long long)r2.x * 32) + c);
      unsigned q3 = *((const unsigned*)(Y2B + (long long)r3.x * 32) + c);
      s0 += bflo(q0) + bflo(q1) + bflo(q2) + bflo(q3);
      s1 += bfhi(q0) + bfhi(q1) + bfhi(q2) + bfhi(q3);
    }
    for (; t < deg; ++t) {
      int2 r = recs[beg + t];
      unsigned q = *((const unsigned*)(Y2B + (long long)r.x * 32) + c);
      s0 += bflo(q); s1 += bfhi(q);
    }
    *(float2*)(S2 + (long long)n * 32 + c * 2) = make_float2(s0, s1);
  }
}

// ---------------- gemm 2 (MFMA): F2@B2 + S2 + fb2s -> out ----------------
__global__ __launch_bounds__(256) void k_gemm2(
    const unsigned short* __restrict__ F2, const unsigned short* __restrict__ PK,
    const float* __restrict__ fb2s, const float* __restrict__ S2,
    const int* __restrict__ flags, void* __restrict__ out) {
  int lane = threadIdx.x & 63;
  int wv = threadIdx.x >> 6;
  int m = lane & 15, quad = lane >> 4;
  int bf = flags[1];
  short8x Bf[6];
#pragma unroll
  for (int s = 0; s < 6; ++s) Bf[s] = *(const short8x*)(PK + 12288 + (s * 64 + lane) * 8);
  long long gw = (long long)blockIdx.x * 4 + wv;
  long long nw = (long long)gridDim.x * 4;
  for (long long tile = gw; tile < NT; tile += nw) {
    long long n0 = tile * 16;
    const unsigned short* f2 = F2 + (n0 + m) * 96 + quad * 8;
    short8x A[3];
#pragma unroll
    for (int cc = 0; cc < 3; ++cc) A[cc] = *(const short8x*)(f2 + cc * 32);
    f32x4 acc[2];
#pragma unroll
    for (int t = 0; t < 2; ++t) {
      float b = fb2s[t * 16 + m];
#pragma unroll
      for (int i = 0; i < 4; ++i)
        acc[t][i] = b + S2[(n0 + quad * 4 + i) * 32 + t * 16 + m];
    }
#pragma unroll
    for (int cc = 0; cc < 3; ++cc) {
#pragma unroll
      for (int t = 0; t < 2; ++t)
        acc[t] = __builtin_amdgcn_mfma_f32_16x16x32_bf16(A[cc], Bf[cc * 2 + t], acc[t], 0, 0, 0);
    }
#pragma unroll
    for (int t = 0; t < 2; ++t) {
#pragma unroll
      for (int i = 0; i < 4; ++i) {
        long long idx = (n0 + quad * 4 + i) * 32 + t * 16 + m;
        if (bf) ((unsigned short*)out)[idx] = f2bf(acc[t][i]);
        else ((float*)out)[idx] = acc[t][i];
      }
    }
  }
}

extern "C" void kernel_launch(void* const* d_in, const int* in_sizes, int n_in,
                              void* d_out, int out_size, void* d_ws, size_t ws_size,
                              hipStream_t stream) {
  const void* x = d_in[0];
  const void* ei = d_in[1];
  const void* ea = d_in[2];
  const void* W1_msg = d_in[3];
  const void* b1_msg = d_in[4];
  const void* W1_self = d_in[5];
  const void* b1_self = d_in[6];
  const void* gamma = d_in[7];
  const void* beta = d_in[8];
  const void* mean = d_in[9];
  const void* var = d_in[10];
  const void* W2_msg = d_in[11];
  const void* b2_msg = d_in[12];
  const void* W2_self = d_in[13];
  const void* b2_self = d_in[14];

  float* ws = (float*)d_ws;
  int* counts = (int*)(ws + OFF_CNT);
  int* row_ptr = (int*)(ws + OFF_ROW);
  int2* recs = (int2*)(ws + OFF_RECS);
  int* flags = (int*)(ws + OFF_FLAGS);
  int* bs = (int*)(ws + OFF_BS);
  int* bo = (int*)(ws + OFF_BO);
  unsigned short* PK = (unsigned short*)(ws + OFF_PK);
  float* fb1s = ws + OFF_FB1S;
  float* fb2s = ws + OFF_FB2S;
  unsigned short* F1 = (unsigned short*)(ws + OFF_F1);
  int2* binbuf = (int2*)(ws + OFF_F1);  // aliases F1 (dead before gather1)
  unsigned short* F2 = (unsigned short*)(ws + OFF_F2);
  unsigned short* Y2B = (unsigned short*)(ws + OFF_Y2B);
  float* S2 = ws + OFF_S2;
  int* bcur = (int*)(ws + OFF_BCUR);

  hipLaunchKernelGGL(k_detect, dim3(1), dim3(64), 0, stream, ei, x, flags);
  hipMemsetAsync(bcur, 0, NBK * sizeof(int), stream);
  hipLaunchKernelGGL(k_prep, dim3(64), dim3(256), 0, stream, W1_msg, b1_msg, W1_self,
                     b1_self, gamma, beta, mean, var, W2_msg, b2_msg, W2_self, b2_self,
                     flags, PK, fb1s, fb2s);

  hipLaunchKernelGGL(k_bin, dim3(256), dim3(256), 0, stream, ei, flags, bcur, binbuf);
  hipLaunchKernelGGL(k_bhist, dim3(NBK), dim3(256), 0, stream, bcur, binbuf, counts);
  hipLaunchKernelGGL(k_scanA, dim3(SCB), dim3(1024), 0, stream, counts, bs);
  hipLaunchKernelGGL(k_scanB, dim3(1), dim3(64), 0, stream, bs, bo);
  hipLaunchKernelGGL(k_scanC, dim3(SCB), dim3(1024), 0, stream, counts, bo, row_ptr);
  hipLaunchKernelGGL(k_place, dim3(NBK), dim3(256), 0, stream, bcur, binbuf, row_ptr,
                     recs);

  int gblocks = (NB4 + 3) / 4;  // 3125 blocks, 4 waves each -> 12500 waves
  hipLaunchKernelGGL(k_gather1, dim3(gblocks), dim3(256), 0, stream, x, ea, row_ptr,
                     recs, flags, F1, F2);
  int mblocks = (NT + 3) / 4;
  hipLaunchKernelGGL(k_gemm1, dim3(mblocks), dim3(256), 0, stream, F1, PK, fb1s, F2,
                     Y2B);
  hipLaunchKernelGGL(k_gather2, dim3(gblocks), dim3(256), 0, stream, Y2B, row_ptr, recs,
                     S2);
  hipLaunchKernelGGL(k_gemm2, dim3(mblocks), dim3(256), 0, stream, F2, PK, fb2s, S2,
                     flags, d_out);
}

// Round 6
// 261.464 us; speedup vs baseline: 1.0191x; 1.0191x over previous
//
#include <hip/hip_runtime.h>

#define NN 50000
#define NE 800000
#define NB 6250        // NN/8 gather batches
#define NT 3125        // NN/16 mfma tiles
#define SCB 49         // ceil(NN/1024) scan blocks
#define NBK 128        // coarse buckets
#define BNODE 391      // nodes per bucket (391*128 = 50048 >= NN)
#define BCAP 7680      // bucket capacity (mean 6250, +18 sigma)
#define SCAP 56        // per-block LDS stage capacity per bucket

typedef __attribute__((ext_vector_type(8))) short short8x;
typedef __attribute__((ext_vector_type(4))) float f32x4;

// ws layout (float-index offsets)
#define OFF_CNT   0LL                 // NN ints (counts)
#define OFF_ROW   ((long long)NN)     // NN+1 ints (row_ptr)
#define OFF_RECS  (3LL*NN + 16)       // NE int2
#define OFF_FLAGS (35LL*NN + 16)      // ints
#define OFF_BS    (35LL*NN + 32)      // 64 ints
#define OFF_BO    (35LL*NN + 96)      // 64 ints
#define OFF_PK    (35LL*NN + 160)     // 15360 ushorts (16B-aligned)
#define OFF_FB1S  (35LL*NN + 7840)    // 64 f32
#define OFF_FB2S  (35LL*NN + 7904)    // 32 f32
#define OFF_F1    (36LL*NN)           // NN*160 bf16  (binbuf aliases this region)
#define OFF_F2    (116LL*NN)          // NN*96 bf16
#define OFF_Y2B   (164LL*NN)          // NN*32 bf16
#define OFF_S2    (180LL*NN)          // NN*32 f32
#define OFF_BCUR  (212LL*NN)          // 128 ints

__device__ __forceinline__ float ldf(const void* p, long long i, int bf16) {
  if (bf16) {
    unsigned short u = ((const unsigned short*)p)[i];
    return __uint_as_float(((unsigned)u) << 16);
  }
  return ((const float*)p)[i];
}
__device__ __forceinline__ unsigned short f2bf(float f) {
  unsigned u = __float_as_uint(f);
  unsigned r = (u + 0x7fffu + ((u >> 16) & 1u)) >> 16;
  return (unsigned short)r;
}
__device__ __forceinline__ unsigned pk2(float lo, float hi) {
  return (unsigned)f2bf(lo) | ((unsigned)f2bf(hi) << 16);
}
__device__ __forceinline__ int ldidx(const void* p, long long i, int i64) {
  return i64 ? (int)((const long long*)p)[i] : ((const int*)p)[i];
}
__device__ __forceinline__ float bflo(unsigned u) { return __uint_as_float(u << 16); }
__device__ __forceinline__ float bfhi(unsigned u) { return __uint_as_float(u & 0xffff0000u); }

// ---------------- detect dtypes ----------------
__global__ void k_detect(const void* ei, const void* x, int* flags) {
  int lane = threadIdx.x & 63;
  const int* p = (const int*)ei;
  int any = 0;
  for (int i = lane; i < 256; i += 64) any |= p[2 * i + 1];
  unsigned long long anyb = __ballot(any != 0);
  const unsigned short* q = (const unsigned short*)x;
  int cnt = 0;
  for (int i = lane; i < 256; i += 64) {
    unsigned short w = q[2 * i];
    int e = (w >> 7) & 0xff;
    if (w == 0 || (e >= 110 && e <= 140)) cnt++;
  }
  for (int m = 1; m < 64; m <<= 1) cnt += __shfl_xor(cnt, m, 64);
  if (lane == 0) {
    flags[0] = (anyb == 0ull) ? 1 : 0;
    flags[1] = (cnt >= 192) ? 1 : 0;
  }
}

// ---------------- pack BN-folded weights into MFMA B-fragment order ----------------
__global__ __launch_bounds__(256) void k_prep(
    const void* __restrict__ W1_msg, const void* __restrict__ b1_msg,
    const void* __restrict__ W1_self, const void* __restrict__ b1_self,
    const void* __restrict__ gamma, const void* __restrict__ beta,
    const void* __restrict__ mean, const void* __restrict__ var,
    const void* __restrict__ W2_msg, const void* __restrict__ b2_msg,
    const void* __restrict__ W2_self, const void* __restrict__ b2_self,
    const int* __restrict__ flags, unsigned short* __restrict__ PK,
    float* __restrict__ fb1s, float* __restrict__ fb2s) {
  int bf = flags[1];
  int t0 = blockIdx.x * 256 + threadIdx.x;
  int stride = gridDim.x * 256;
  for (int i = t0; i < 10240; i += stride) {
    int j = i & 7, L = (i >> 3) & 63, t = (i >> 9) & 3, c = i >> 11;
    int k = c * 32 + ((L >> 4) << 3) + j;
    int col = t * 16 + (L & 15);
    float sc = ldf(gamma, col, bf) * rsqrtf(ldf(var, col, bf) + 1e-5f);
    float v;
    if (k < 64) v = ldf(W1_msg, k * 64 + col, bf) * sc;
    else if (k < 128) v = ldf(W1_self, (k - 64) * 64 + col, bf) * sc;
    else if (k < 144) v = ldf(W1_msg, (64 + k - 128) * 64 + col, bf) * sc;
    else if (k == 144) v = ldf(b1_msg, col, bf) * sc;
    else v = 0.0f;
    PK[i] = f2bf(v);
  }
  for (int i = t0; i < 2048; i += stride) {
    int j = i & 7, L = (i >> 3) & 63, t = (i >> 9) & 1, c = i >> 10;
    int k = c * 32 + ((L >> 4) << 3) + j;
    int col = t * 16 + (L & 15);
    PK[10240 + i] = f2bf(ldf(W2_msg, k * 32 + col, bf));
  }
  for (int i = t0; i < 3072; i += stride) {
    int j = i & 7, L = (i >> 3) & 63, t = (i >> 9) & 1, c = i >> 10;
    int k = c * 32 + ((L >> 4) << 3) + j;
    int col = t * 16 + (L & 15);
    float v;
    if (k < 64) v = ldf(W2_self, k * 32 + col, bf);
    else if (k < 80) v = ldf(W2_msg, k * 32 + col, bf);
    else if (k == 80) v = ldf(b2_msg, col, bf);
    else v = 0.0f;
    PK[12288 + i] = f2bf(v);
  }
  for (int i = t0; i < 64; i += stride) {
    float sc = ldf(gamma, i, bf) * rsqrtf(ldf(var, i, bf) + 1e-5f);
    fb1s[i] = ldf(b1_self, i, bf) * sc + ldf(beta, i, bf) - ldf(mean, i, bf) * sc;
  }
  for (int i = t0; i < 32; i += stride) fb2s[i] = ldf(b2_self, i, bf);
}

// ---------------- phase 1: LDS-staged binning by dst/391 ----------------
__global__ __launch_bounds__(256) void k_bin(const void* __restrict__ ei,
                                             const int* __restrict__ flags,
                                             int* __restrict__ bcur,
                                             int2* __restrict__ binbuf) {
  __shared__ int2 stage[NBK][SCAP];  // 57.3 KB
  __shared__ int scnt[NBK];
  __shared__ int gbase[NBK];
  int tid = threadIdx.x;
  for (int i = tid; i < NBK; i += 256) scnt[i] = 0;
  __syncthreads();
  int i64 = flags[0];
  for (long long e0 = (long long)blockIdx.x * 256; e0 < NE;
       e0 += (long long)gridDim.x * 256) {
    long long e = e0 + tid;
    if (e < NE) {
      int src = ldidx(ei, e, i64);
      int dst = ldidx(ei, NE + e, i64);
      int b = dst / BNODE;
      int dl = dst - b * BNODE;
      int2 ent = make_int2(src | (dl << 16), (int)e);
      int pos = atomicAdd(&scnt[b], 1);
      if (pos < SCAP) {
        stage[b][pos] = ent;
      } else {  // rare overflow: direct global placement
        int gp = atomicAdd(&bcur[b], 1);
        binbuf[(long long)b * BCAP + gp] = ent;
      }
    }
  }
  __syncthreads();
  if (tid < NBK) {
    int cb = scnt[tid] < SCAP ? scnt[tid] : SCAP;
    gbase[tid] = atomicAdd(&bcur[tid], cb);
  }
  __syncthreads();
  for (int b = 0; b < NBK; ++b) {
    int cb = scnt[b] < SCAP ? scnt[b] : SCAP;
    for (int i = tid; i < cb; i += 256)
      binbuf[(long long)b * BCAP + gbase[b] + i] = stage[b][i];
  }
}

// ---------------- phase 1.5: per-bucket LDS histogram -> counts ----------------
__global__ __launch_bounds__(256) void k_bhist(const int* __restrict__ bcur,
                                               const int2* __restrict__ binbuf,
                                               int* __restrict__ counts) {
  __shared__ int lh[BNODE];
  int b = blockIdx.x;
  int tid = threadIdx.x;
  for (int i = tid; i < BNODE; i += 256) lh[i] = 0;
  __syncthreads();
  int cnt = bcur[b];
  for (int i = tid; i < cnt; i += 256) {
    int dl = (binbuf[(long long)b * BCAP + i].x >> 16) & 0x3FF;
    atomicAdd(&lh[dl], 1);
  }
  __syncthreads();
  int base = b * BNODE;
  int nn = NN - base < BNODE ? NN - base : BNODE;
  for (int i = tid; i < nn; i += 256) counts[base + i] = lh[i];
}

// ---------------- scan (3 phases) ----------------
__global__ __launch_bounds__(1024) void k_scanA(const int* __restrict__ counts,
                                                int* __restrict__ bs) {
  __shared__ int sd[1024];
  int t = threadIdx.x;
  int i = blockIdx.x * 1024 + t;
  sd[t] = (i < NN) ? counts[i] : 0;
  __syncthreads();
  for (int off = 512; off > 0; off >>= 1) {
    if (t < off) sd[t] += sd[t + off];
    __syncthreads();
  }
  if (t == 0) bs[blockIdx.x] = sd[0];
}

__global__ void k_scanB(const int* __restrict__ bs, int* __restrict__ bo) {
  int lane = threadIdx.x & 63;
  int v = (lane < SCB) ? bs[lane] : 0;
  int orig = v;
  for (int off = 1; off < 64; off <<= 1) {
    int u = __shfl_up(v, off, 64);
    if (lane >= off) v += u;
  }
  if (lane < SCB) bo[lane] = v - orig;
}

__global__ __launch_bounds__(1024) void k_scanC(const int* __restrict__ counts,
                                                const int* __restrict__ bo,
                                                int* __restrict__ row_ptr) {
  __shared__ int sd[1024];
  int t = threadIdx.x;
  int i = blockIdx.x * 1024 + t;
  int v = (i < NN) ? counts[i] : 0;
  sd[t] = v;
  __syncthreads();
  for (int off = 1; off < 1024; off <<= 1) {
    int u = (t >= off) ? sd[t - off] : 0;
    __syncthreads();
    sd[t] += u;
    __syncthreads();
  }
  int excl = sd[t] - v + bo[blockIdx.x];
  if (i < NN) row_ptr[i] = excl;
  if (i == NN - 1) row_ptr[NN] = excl + v;
}

// ---------------- phase 2: per-bucket LDS placement -> recs (coalesced) ----------------
__global__ __launch_bounds__(256) void k_place(const int* __restrict__ bcur,
                                               const int2* __restrict__ binbuf,
                                               const int* __restrict__ row_ptr,
                                               int2* __restrict__ recs) {
  __shared__ int2 outb[BCAP];  // 60 KB
  __shared__ int lcur[BNODE];
  int b = blockIdx.x;
  int tid = threadIdx.x;
  int base = b * BNODE;
  int nn = NN - base < BNODE ? NN - base : BNODE;
  int rbase = row_ptr[base];
  for (int i = tid; i < nn; i += 256) lcur[i] = row_ptr[base + i] - rbase;
  __syncthreads();
  int cnt = bcur[b];
  for (int i = tid; i < cnt; i += 256) {
    int2 ent = binbuf[(long long)b * BCAP + i];
    int dl = (ent.x >> 16) & 0x3FF;
    int p = atomicAdd(&lcur[dl], 1);
    outb[p] = make_int2(ent.x & 0xFFFF, ent.y);
  }
  __syncthreads();
  for (int i = tid; i < cnt; i += 256) recs[rbase + i] = outb[i];
}

// ---------------- gather 1: 8 lanes/node, unroll-8 (round-2 structure, deeper MLP) ----------------
// uint4 x-loads / uint2 ea-loads / plain stores / natural order — all proven in r2.
// __launch_bounds__(256,4): pin >=4 waves/EU (16/CU) so VGPR stays <=128 (no cliff).
__global__ __launch_bounds__(256, 4) void k_gather1(
    const void* __restrict__ x, const void* __restrict__ ea,
    const int* __restrict__ row_ptr, const int2* __restrict__ recs,
    const int* __restrict__ flags, unsigned short* __restrict__ F1,
    unsigned short* __restrict__ F2) {
  int lane = threadIdx.x & 63;
  int g = lane >> 3, c = lane & 7;
  int bf = flags[1];
  long long wid = ((long long)blockIdx.x * blockDim.x + threadIdx.x) >> 6;
  long long nw = ((long long)gridDim.x * blockDim.x) >> 6;
  for (long long b = wid; b < NB; b += nw) {
    int n = (int)(b * 8 + g);
    int beg = row_ptr[n];
    int deg = row_ptr[n + 1] - beg;
    float a0 = 0.f, a1 = 0.f, a2 = 0.f, a3 = 0.f, a4 = 0.f, a5 = 0.f, a6 = 0.f, a7 = 0.f;
    float e0 = 0.f, e1 = 0.f, e2 = 0.f, e3 = 0.f;
    uint4 xw;
    if (bf) {
      const unsigned short* xs = (const unsigned short*)x;
      const unsigned short* es = (const unsigned short*)ea;
      int t = 0;
      for (; t + 8 <= deg; t += 8) {
        int2 r0 = recs[beg + t + 0];
        int2 r1 = recs[beg + t + 1];
        int2 r2 = recs[beg + t + 2];
        int2 r3 = recs[beg + t + 3];
        int2 r4 = recs[beg + t + 4];
        int2 r5 = recs[beg + t + 5];
        int2 r6 = recs[beg + t + 6];
        int2 r7 = recs[beg + t + 7];
        uint4 w0 = *((const uint4*)(xs + ((long long)r0.x << 6)) + c);
        uint4 w1 = *((const uint4*)(xs + ((long long)r1.x << 6)) + c);
        uint4 w2 = *((const uint4*)(xs + ((long long)r2.x << 6)) + c);
        uint4 w3 = *((const uint4*)(xs + ((long long)r3.x << 6)) + c);
        uint4 w4 = *((const uint4*)(xs + ((long long)r4.x << 6)) + c);
        uint4 w5 = *((const uint4*)(xs + ((long long)r5.x << 6)) + c);
        uint4 w6 = *((const uint4*)(xs + ((long long)r6.x << 6)) + c);
        uint4 w7 = *((const uint4*)(xs + ((long long)r7.x << 6)) + c);
        a0 += (bflo(w0.x) + bflo(w1.x)) + (bflo(w2.x) + bflo(w3.x)) +
              (bflo(w4.x) + bflo(w5.x)) + (bflo(w6.x) + bflo(w7.x));
        a1 += (bfhi(w0.x) + bfhi(w1.x)) + (bfhi(w2.x) + bfhi(w3.x)) +
              (bfhi(w4.x) + bfhi(w5.x)) + (bfhi(w6.x) + bfhi(w7.x));
        a2 += (bflo(w0.y) + bflo(w1.y)) + (bflo(w2.y) + bflo(w3.y)) +
              (bflo(w4.y) + bflo(w5.y)) + (bflo(w6.y) + bflo(w7.y));
        a3 += (bfhi(w0.y) + bfhi(w1.y)) + (bfhi(w2.y) + bfhi(w3.y)) +
              (bfhi(w4.y) + bfhi(w5.y)) + (bfhi(w6.y) + bfhi(w7.y));
        a4 += (bflo(w0.z) + bflo(w1.z)) + (bflo(w2.z) + bflo(w3.z)) +
              (bflo(w4.z) + bflo(w5.z)) + (bflo(w6.z) + bflo(w7.z));
        a5 += (bfhi(w0.z) + bfhi(w1.z)) + (bfhi(w2.z) + bfhi(w3.z)) +
              (bfhi(w4.z) + bfhi(w5.z)) + (bfhi(w6.z) + bfhi(w7.z));
        a6 += (bflo(w0.w) + bflo(w1.w)) + (bflo(w2.w) + bflo(w3.w)) +
              (bflo(w4.w) + bflo(w5.w)) + (bflo(w6.w) + bflo(w7.w));
        a7 += (bfhi(w0.w) + bfhi(w1.w)) + (bfhi(w2.w) + bfhi(w3.w)) +
              (bfhi(w4.w) + bfhi(w5.w)) + (bfhi(w6.w) + bfhi(w7.w));
        if (c < 4) {
          uint2 q0 = *((const uint2*)(es + ((long long)r0.y << 4)) + c);
          uint2 q1 = *((const uint2*)(es + ((long long)r1.y << 4)) + c);
          uint2 q2 = *((const uint2*)(es + ((long long)r2.y << 4)) + c);
          uint2 q3 = *((const uint2*)(es + ((long long)r3.y << 4)) + c);
          uint2 q4 = *((const uint2*)(es + ((long long)r4.y << 4)) + c);
          uint2 q5 = *((const uint2*)(es + ((long long)r5.y << 4)) + c);
          uint2 q6 = *((const uint2*)(es + ((long long)r6.y << 4)) + c);
          uint2 q7 = *((const uint2*)(es + ((long long)r7.y << 4)) + c);
          e0 += (bflo(q0.x) + bflo(q1.x)) + (bflo(q2.x) + bflo(q3.x)) +
                (bflo(q4.x) + bflo(q5.x)) + (bflo(q6.x) + bflo(q7.x));
          e1 += (bfhi(q0.x) + bfhi(q1.x)) + (bfhi(q2.x) + bfhi(q3.x)) +
                (bfhi(q4.x) + bfhi(q5.x)) + (bfhi(q6.x) + bfhi(q7.x));
          e2 += (bflo(q0.y) + bflo(q1.y)) + (bflo(q2.y) + bflo(q3.y)) +
                (bflo(q4.y) + bflo(q5.y)) + (bflo(q6.y) + bflo(q7.y));
          e3 += (bfhi(q0.y) + bfhi(q1.y)) + (bfhi(q2.y) + bfhi(q3.y)) +
                (bfhi(q4.y) + bfhi(q5.y)) + (bfhi(q6.y) + bfhi(q7.y));
        }
      }
      for (; t + 4 <= deg; t += 4) {
        int2 r0 = recs[beg + t + 0];
        int2 r1 = recs[beg + t + 1];
        int2 r2 = recs[beg + t + 2];
        int2 r3 = recs[beg + t + 3];
        uint4 w0 = *((const uint4*)(xs + ((long long)r0.x << 6)) + c);
        uint4 w1 = *((const uint4*)(xs + ((long long)r1.x << 6)) + c);
        uint4 w2 = *((const uint4*)(xs + ((long long)r2.x << 6)) + c);
        uint4 w3 = *((const uint4*)(xs + ((long long)r3.x << 6)) + c);
        a0 += bflo(w0.x) + bflo(w1.x) + bflo(w2.x) + bflo(w3.x);
        a1 += bfhi(w0.x) + bfhi(w1.x) + bfhi(w2.x) + bfhi(w3.x);
        a2 += bflo(w0.y) + bflo(w1.y) + bflo(w2.y) + bflo(w3.y);
        a3 += bfhi(w0.y) + bfhi(w1.y) + bfhi(w2.y) + bfhi(w3.y);
        a4 += bflo(w0.z) + bflo(w1.z) + bflo(w2.z) + bflo(w3.z);
        a5 += bfhi(w0.z) + bfhi(w1.z) + bfhi(w2.z) + bfhi(w3.z);
        a6 += bflo(w0.w) + bflo(w1.w) + bflo(w2.w) + bflo(w3.w);
        a7 += bfhi(w0.w) + bfhi(w1.w) + bfhi(w2.w) + bfhi(w3.w);
        if (c < 4) {
          uint2 q0 = *((const uint2*)(es + ((long long)r0.y << 4)) + c);
          uint2 q1 = *((const uint2*)(es + ((long long)r1.y << 4)) + c);
          uint2 q2 = *((const uint2*)(es + ((long long)r2.y << 4)) + c);
          uint2 q3 = *((const uint2*)(es + ((long long)r3.y << 4)) + c);
          e0 += bflo(q0.x) + bflo(q1.x) + bflo(q2.x) + bflo(q3.x);
          e1 += bfhi(q0.x) + bfhi(q1.x) + bfhi(q2.x) + bfhi(q3.x);
          e2 += bflo(q0.y) + bflo(q1.y) + bflo(q2.y) + bflo(q3.y);
          e3 += bfhi(q0.y) + bfhi(q1.y) + bfhi(q2.y) + bfhi(q3.y);
        }
      }
      for (; t < deg; ++t) {
        int2 r = recs[beg + t];
        uint4 w = *((const uint4*)(xs + ((long long)r.x << 6)) + c);
        a0 += bflo(w.x); a1 += bfhi(w.x);
        a2 += bflo(w.y); a3 += bfhi(w.y);
        a4 += bflo(w.z); a5 += bfhi(w.z);
        a6 += bflo(w.w); a7 += bfhi(w.w);
        if (c < 4) {
          uint2 q = *((const uint2*)(es + ((long long)r.y << 4)) + c);
          e0 += bflo(q.x); e1 += bfhi(q.x);
          e2 += bflo(q.y); e3 += bfhi(q.y);
        }
      }
      xw = *((const uint4*)(xs + ((long long)n << 6)) + c);
    } else {
      const float* xf = (const float*)x;
      const float* ef = (const float*)ea;
      for (int t = 0; t < deg; ++t) {
        int2 r = recs[beg + t];
        float4 w0 = *((const float4*)(xf + ((long long)r.x << 6)) + c * 2);
        float4 w1 = *((const float4*)(xf + ((long long)r.x << 6)) + c * 2 + 1);
        a0 += w0.x; a1 += w0.y; a2 += w0.z; a3 += w0.w;
        a4 += w1.x; a5 += w1.y; a6 += w1.z; a7 += w1.w;
        if (c < 4) {
          float4 q = *((const float4*)(ef + ((long long)r.y << 4)) + c);
          e0 += q.x; e1 += q.y; e2 += q.z; e3 += q.w;
        }
      }
      float4 p0 = *((const float4*)(xf + ((long long)n << 6)) + c * 2);
      float4 p1 = *((const float4*)(xf + ((long long)n << 6)) + c * 2 + 1);
      xw = make_uint4(pk2(p0.x, p0.y), pk2(p0.z, p0.w), pk2(p1.x, p1.y), pk2(p1.z, p1.w));
    }
    unsigned short* f1 = F1 + (long long)n * 160;
    unsigned short* f2 = F2 + (long long)n * 96;
    *((uint4*)f1 + c) = make_uint4(pk2(a0, a1), pk2(a2, a3), pk2(a4, a5), pk2(a6, a7));
    *((uint4*)(f1 + 64) + c) = xw;
    if (c < 4) {
      uint2 sp = make_uint2(pk2(e0, e1), pk2(e2, e3));
      *((uint2*)(f1 + 128) + c) = sp;
      *((uint2*)(f2 + 64) + c) = sp;
    }
    if (c == 4) {
      unsigned d = (unsigned)f2bf((float)deg);
      *((uint4*)(f1 + 144)) = make_uint4(d, 0u, 0u, 0u);
      *((uint4*)(f2 + 80)) = make_uint4(d, 0u, 0u, 0u);
    }
    if (c == 5) {
      *((uint4*)(f1 + 152)) = make_uint4(0u, 0u, 0u, 0u);
      *((uint4*)(f2 + 88)) = make_uint4(0u, 0u, 0u, 0u);
    }
  }
}

// ---------------- gemm 1 (MFMA): F1@B1 + bias -> ReLU -> F2[0..64) ; fused Y2 = h@BY ----------------
__global__ __launch_bounds__(256) void k_gemm1(
    const unsigned short* __restrict__ F1, const unsigned short* __restrict__ PK,
    const float* __restrict__ fb1s, unsigned short* __restrict__ F2,
    unsigned short* __restrict__ Y2B) {
  // per-wave LDS staging for the h-tile transpose (stride 72 shorts = conflict-light)
  __shared__ unsigned short hsh[4][16 * 72];
  int lane = threadIdx.x & 63;
  int wv = threadIdx.x >> 6;
  int m = lane & 15, quad = lane >> 4;
  unsigned short* hs = hsh[wv];
  short8x Bf[20];
#pragma unroll
  for (int s = 0; s < 20; ++s) Bf[s] = *(const short8x*)(PK + (s * 64 + lane) * 8);
  short8x By[4];
#pragma unroll
  for (int s = 0; s < 4; ++s) By[s] = *(const short8x*)(PK + 10240 + (s * 64 + lane) * 8);
  long long gw = (long long)blockIdx.x * 4 + wv;
  long long nw = (long long)gridDim.x * 4;
  for (long long tile = gw; tile < NT; tile += nw) {
    long long n0 = tile * 16;
    const unsigned short* f1 = F1 + (n0 + m) * 160 + quad * 8;
    short8x A[5];
#pragma unroll
    for (int cc = 0; cc < 5; ++cc) A[cc] = *(const short8x*)(f1 + cc * 32);
    f32x4 acc[4];
#pragma unroll
    for (int t = 0; t < 4; ++t) {
      float b = fb1s[t * 16 + m];
      acc[t] = (f32x4){b, b, b, b};
    }
#pragma unroll
    for (int cc = 0; cc < 5; ++cc) {
#pragma unroll
      for (int t = 0; t < 4; ++t)
        acc[t] = __builtin_amdgcn_mfma_f32_16x16x32_bf16(A[cc], Bf[cc * 4 + t], acc[t], 0, 0, 0);
    }
    // write h to F2 (plain, stays in L2 for gemm2) and stage bf16-rounded h in LDS
#pragma unroll
    for (int t = 0; t < 4; ++t) {
#pragma unroll
      for (int i = 0; i < 4; ++i) {
        float h = fmaxf(acc[t][i], 0.0f);
        unsigned short us = f2bf(h);
        F2[(n0 + quad * 4 + i) * 96 + t * 16 + m] = us;
        hs[(quad * 4 + i) * 72 + t * 16 + m] = us;
      }
    }
    __builtin_amdgcn_sched_barrier(0);  // keep ds_reads after ds_writes (wave-synchronous)
    f32x4 yacc[2];
    yacc[0] = (f32x4){0.f, 0.f, 0.f, 0.f};
    yacc[1] = (f32x4){0.f, 0.f, 0.f, 0.f};
#pragma unroll
    for (int cc = 0; cc < 2; ++cc) {
      short8x Ah = *(const short8x*)(hs + m * 72 + cc * 32 + quad * 8);
#pragma unroll
      for (int t = 0; t < 2; ++t)
        yacc[t] = __builtin_amdgcn_mfma_f32_16x16x32_bf16(Ah, By[cc * 2 + t], yacc[t], 0, 0, 0);
    }
#pragma unroll
    for (int t = 0; t < 2; ++t) {
#pragma unroll
      for (int i = 0; i < 4; ++i)
        Y2B[(n0 + quad * 4 + i) * 32 + t * 16 + m] = f2bf(yacc[t][i]);
    }
    __builtin_amdgcn_sched_barrier(0);
  }
}

// ---------------- gather 2: 8 lanes/node, unroll-8 (round-2 structure, deeper MLP) ----------------
__global__ __launch_bounds__(256, 4) void k_gather2(
    const unsigned short* __restrict__ Y2B, const int* __restrict__ row_ptr,
    const int2* __restrict__ recs, float* __restrict__ S2) {
  int lane = threadIdx.x & 63;
  int g = lane >> 3, c = lane & 7;
  long long wid = ((long long)blockIdx.x * blockDim.x + threadIdx.x) >> 6;
  long long nw = ((long long)gridDim.x * blockDim.x) >> 6;
  for (long long b = wid; b < NB; b += nw) {
    int n = (int)(b * 8 + g);
    int beg = row_ptr[n];
    int deg = row_ptr[n + 1] - beg;
    float s0 = 0.f, s1 = 0.f, s2 = 0.f, s3 = 0.f;
    int t = 0;
    for (; t + 8 <= deg; t += 8) {
      int2 r0 = recs[beg + t + 0];
      int2 r1 = recs[beg + t + 1];
      int2 r2 = recs[beg + t + 2];
      int2 r3 = recs[beg + t + 3];
      int2 r4 = recs[beg + t + 4];
      int2 r5 = recs[beg + t + 5];
      int2 r6 = recs[beg + t + 6];
      int2 r7 = recs[beg + t + 7];
      uint2 q0 = *((const uint2*)(Y2B + (long long)r0.x * 32) + c);
      uint2 q1 = *((const uint2*)(Y2B + (long long)r1.x * 32) + c);
      uint2 q2 = *((const uint2*)(Y2B + (long long)r2.x * 32) + c);
      uint2 q3 = *((const uint2*)(Y2B + (long long)r3.x * 32) + c);
      uint2 q4 = *((const uint2*)(Y2B + (long long)r4.x * 32) + c);
      uint2 q5 = *((const uint2*)(Y2B + (long long)r5.x * 32) + c);
      uint2 q6 = *((const uint2*)(Y2B + (long long)r6.x * 32) + c);
      uint2 q7 = *((const uint2*)(Y2B + (long long)r7.x * 32) + c);
      s0 += (bflo(q0.x) + bflo(q1.x)) + (bflo(q2.x) + bflo(q3.x)) +
            (bflo(q4.x) + bflo(q5.x)) + (bflo(q6.x) + bflo(q7.x));
      s1 += (bfhi(q0.x) + bfhi(q1.x)) + (bfhi(q2.x) + bfhi(q3.x)) +
            (bfhi(q4.x) + bfhi(q5.x)) + (bfhi(q6.x) + bfhi(q7.x));
      s2 += (bflo(q0.y) + bflo(q1.y)) + (bflo(q2.y) + bflo(q3.y)) +
            (bflo(q4.y) + bflo(q5.y)) + (bflo(q6.y) + bflo(q7.y));
      s3 += (bfhi(q0.y) + bfhi(q1.y)) + (bfhi(q2.y) + bfhi(q3.y)) +
            (bfhi(q4.y) + bfhi(q5.y)) + (bfhi(q6.y) + bfhi(q7.y));
    }
    for (; t + 4 <= deg; t += 4) {
      int2 r0 = recs[beg + t + 0];
      int2 r1 = recs[beg + t + 1];
      int2 r2 = recs[beg + t + 2];
      int2 r3 = recs[beg + t + 3];
      uint2 q0 = *((const uint2*)(Y2B + (long long)r0.x * 32) + c);
      uint2 q1 = *((const uint2*)(Y2B + (long long)r1.x * 32) + c);
      uint2 q2 = *((const uint2*)(Y2B + (long long)r2.x * 32) + c);
      uint2 q3 = *((const uint2*)(Y2B + (long long)r3.x * 32) + c);
      s0 += bflo(q0.x) + bflo(q1.x) + bflo(q2.x) + bflo(q3.x);
      s1 += bfhi(q0.x) + bfhi(q1.x) + bfhi(q2.x) + bfhi(q3.x);
      s2 += bflo(q0.y) + bflo(q1.y) + bflo(q2.y) + bflo(q3.y);
      s3 += bfhi(q0.y) + bfhi(q1.y) + bfhi(q2.y) + bfhi(q3.y);
    }
    for (; t < deg; ++t) {
      int2 r = recs[beg + t];
      uint2 q = *((const uint2*)(Y2B + (long long)r.x * 32) + c);
      s0 += bflo(q.x); s1 += bfhi(q.x);
      s2 += bflo(q.y); s3 += bfhi(q.y);
    }
    *(float4*)(S2 + (long long)n * 32 + c * 4) = make_float4(s0, s1, s2, s3);
  }
}

// ---------------- gemm 2 (MFMA): F2@B2 + S2 + fb2s -> out ----------------
__global__ __launch_bounds__(256) void k_gemm2(
    const unsigned short* __restrict__ F2, const unsigned short* __restrict__ PK,
    const float* __restrict__ fb2s, const float* __restrict__ S2,
    const int* __restrict__ flags, void* __restrict__ out) {
  int lane = threadIdx.x & 63;
  int wv = threadIdx.x >> 6;
  int m = lane & 15, quad = lane >> 4;
  int bf = flags[1];
  short8x Bf[6];
#pragma unroll
  for (int s = 0; s < 6; ++s) Bf[s] = *(const short8x*)(PK + 12288 + (s * 64 + lane) * 8);
  long long gw = (long long)blockIdx.x * 4 + wv;
  long long nw = (long long)gridDim.x * 4;
  for (long long tile = gw; tile < NT; tile += nw) {
    long long n0 = tile * 16;
    const unsigned short* f2 = F2 + (n0 + m) * 96 + quad * 8;
    short8x A[3];
#pragma unroll
    for (int cc = 0; cc < 3; ++cc) A[cc] = *(const short8x*)(f2 + cc * 32);
    f32x4 acc[2];
#pragma unroll
    for (int t = 0; t < 2; ++t) {
      float b = fb2s[t * 16 + m];
#pragma unroll
      for (int i = 0; i < 4; ++i)
        acc[t][i] = b + S2[(n0 + quad * 4 + i) * 32 + t * 16 + m];
    }
#pragma unroll
    for (int cc = 0; cc < 3; ++cc) {
#pragma unroll
      for (int t = 0; t < 2; ++t)
        acc[t] = __builtin_amdgcn_mfma_f32_16x16x32_bf16(A[cc], Bf[cc * 2 + t], acc[t], 0, 0, 0);
    }
#pragma unroll
    for (int t = 0; t < 2; ++t) {
#pragma unroll
      for (int i = 0; i < 4; ++i) {
        long long idx = (n0 + quad * 4 + i) * 32 + t * 16 + m;
        if (bf) ((unsigned short*)out)[idx] = f2bf(acc[t][i]);
        else ((float*)out)[idx] = acc[t][i];
      }
    }
  }
}

extern "C" void kernel_launch(void* const* d_in, const int* in_sizes, int n_in,
                              void* d_out, int out_size, void* d_ws, size_t ws_size,
                              hipStream_t stream) {
  const void* x = d_in[0];
  const void* ei = d_in[1];
  const void* ea = d_in[2];
  const void* W1_msg = d_in[3];
  const void* b1_msg = d_in[4];
  const void* W1_self = d_in[5];
  const void* b1_self = d_in[6];
  const void* gamma = d_in[7];
  const void* beta = d_in[8];
  const void* mean = d_in[9];
  const void* var = d_in[10];
  const void* W2_msg = d_in[11];
  const void* b2_msg = d_in[12];
  const void* W2_self = d_in[13];
  const void* b2_self = d_in[14];

  float* ws = (float*)d_ws;
  int* counts = (int*)(ws + OFF_CNT);
  int* row_ptr = (int*)(ws + OFF_ROW);
  int2* recs = (int2*)(ws + OFF_RECS);
  int* flags = (int*)(ws + OFF_FLAGS);
  int* bs = (int*)(ws + OFF_BS);
  int* bo = (int*)(ws + OFF_BO);
  unsigned short* PK = (unsigned short*)(ws + OFF_PK);
  float* fb1s = ws + OFF_FB1S;
  float* fb2s = ws + OFF_FB2S;
  unsigned short* F1 = (unsigned short*)(ws + OFF_F1);
  int2* binbuf = (int2*)(ws + OFF_F1);  // aliases F1 (dead before gather1)
  unsigned short* F2 = (unsigned short*)(ws + OFF_F2);
  unsigned short* Y2B = (unsigned short*)(ws + OFF_Y2B);
  float* S2 = ws + OFF_S2;
  int* bcur = (int*)(ws + OFF_BCUR);

  hipLaunchKernelGGL(k_detect, dim3(1), dim3(64), 0, stream, ei, x, flags);
  hipMemsetAsync(bcur, 0, NBK * sizeof(int), stream);
  hipLaunchKernelGGL(k_prep, dim3(64), dim3(256), 0, stream, W1_msg, b1_msg, W1_self,
                     b1_self, gamma, beta, mean, var, W2_msg, b2_msg, W2_self, b2_self,
                     flags, PK, fb1s, fb2s);

  hipLaunchKernelGGL(k_bin, dim3(256), dim3(256), 0, stream, ei, flags, bcur, binbuf);
  hipLaunchKernelGGL(k_bhist, dim3(NBK), dim3(256), 0, stream, bcur, binbuf, counts);
  hipLaunchKernelGGL(k_scanA, dim3(SCB), dim3(1024), 0, stream, counts, bs);
  hipLaunchKernelGGL(k_scanB, dim3(1), dim3(64), 0, stream, bs, bo);
  hipLaunchKernelGGL(k_scanC, dim3(SCB), dim3(1024), 0, stream, counts, bo, row_ptr);
  hipLaunchKernelGGL(k_place, dim3(NBK), dim3(256), 0, stream, bcur, binbuf, row_ptr,
                     recs);

  int gblocks = (NB + 3) / 4;
  hipLaunchKernelGGL(k_gather1, dim3(gblocks), dim3(256), 0, stream, x, ea, row_ptr,
                     recs, flags, F1, F2);
  int mblocks = (NT + 3) / 4;
  hipLaunchKernelGGL(k_gemm1, dim3(mblocks), dim3(256), 0, stream, F1, PK, fb1s, F2,
                     Y2B);
  hipLaunchKernelGGL(k_gather2, dim3(gblocks), dim3(256), 0, stream, Y2B, row_ptr, recs,
                     S2);
  hipLaunchKernelGGL(k_gemm2, dim3(mblocks), dim3(256), 0, stream, F2, PK, fb2s, S2,
                     flags, d_out);
}

// Round 7
// 241.428 us; speedup vs baseline: 1.1037x; 1.0830x over previous
//
#include <hip/hip_runtime.h>

#define NN 50000
#define NE 800000
#define NB 6250        // NN/8 gather batches
#define NT 3125        // NN/16 mfma tiles
#define NBK 128        // coarse buckets
#define BNODE 391      // nodes per bucket (391*128 = 50048 >= NN)
#define BCAP 7680      // bucket capacity (mean 6250, +18 sigma)
#define SCAP 56        // per-block LDS stage capacity per bucket

typedef __attribute__((ext_vector_type(8))) short short8x;
typedef __attribute__((ext_vector_type(4))) float f32x4;

// ws layout (float-index offsets)
#define OFF_CNT   0LL                 // NN ints (unused now, kept for layout stability)
#define OFF_ROW   ((long long)NN)     // NN+1 ints (row_ptr)
#define OFF_RECS  (3LL*NN + 16)       // NE int2
#define OFF_FLAGS (35LL*NN + 16)      // ints
#define OFF_BS    (35LL*NN + 32)      // 64 ints (unused)
#define OFF_BO    (35LL*NN + 96)      // 128 ints (bucket base offsets)
#define OFF_PK    (35LL*NN + 256)     // 15360 ushorts (16B-aligned)
#define OFF_FB1S  (35LL*NN + 7936)    // 64 f32
#define OFF_FB2S  (35LL*NN + 8000)    // 32 f32
#define OFF_F1    (36LL*NN)           // NN*160 bf16  (binbuf aliases this region)
#define OFF_F2    (116LL*NN)          // NN*96 bf16
#define OFF_Y2B   (164LL*NN)          // NN*32 bf16
#define OFF_S2    (180LL*NN)          // NN*32 f32
#define OFF_BCUR  (212LL*NN)          // 128 ints

__device__ __forceinline__ float ldf(const void* p, long long i, int bf16) {
  if (bf16) {
    unsigned short u = ((const unsigned short*)p)[i];
    return __uint_as_float(((unsigned)u) << 16);
  }
  return ((const float*)p)[i];
}
__device__ __forceinline__ unsigned short f2bf(float f) {
  unsigned u = __float_as_uint(f);
  unsigned r = (u + 0x7fffu + ((u >> 16) & 1u)) >> 16;
  return (unsigned short)r;
}
__device__ __forceinline__ unsigned pk2(float lo, float hi) {
  return (unsigned)f2bf(lo) | ((unsigned)f2bf(hi) << 16);
}
__device__ __forceinline__ int ldidx(const void* p, long long i, int i64) {
  return i64 ? (int)((const long long*)p)[i] : ((const int*)p)[i];
}
__device__ __forceinline__ float bflo(unsigned u) { return __uint_as_float(u << 16); }
__device__ __forceinline__ float bfhi(unsigned u) { return __uint_as_float(u & 0xffff0000u); }

// ---------------- detect dtypes ----------------
__global__ void k_detect(const void* ei, const void* x, int* flags) {
  int lane = threadIdx.x & 63;
  const int* p = (const int*)ei;
  int any = 0;
  for (int i = lane; i < 256; i += 64) any |= p[2 * i + 1];
  unsigned long long anyb = __ballot(any != 0);
  const unsigned short* q = (const unsigned short*)x;
  int cnt = 0;
  for (int i = lane; i < 256; i += 64) {
    unsigned short w = q[2 * i];
    int e = (w >> 7) & 0xff;
    if (w == 0 || (e >= 110 && e <= 140)) cnt++;
  }
  for (int m = 1; m < 64; m <<= 1) cnt += __shfl_xor(cnt, m, 64);
  if (lane == 0) {
    flags[0] = (anyb == 0ull) ? 1 : 0;
    flags[1] = (cnt >= 192) ? 1 : 0;
  }
}

// ---------------- pack BN-folded weights into MFMA B-fragment order ----------------
__global__ __launch_bounds__(256) void k_prep(
    const void* __restrict__ W1_msg, const void* __restrict__ b1_msg,
    const void* __restrict__ W1_self, const void* __restrict__ b1_self,
    const void* __restrict__ gamma, const void* __restrict__ beta,
    const void* __restrict__ mean, const void* __restrict__ var,
    const void* __restrict__ W2_msg, const void* __restrict__ b2_msg,
    const void* __restrict__ W2_self, const void* __restrict__ b2_self,
    const int* __restrict__ flags, unsigned short* __restrict__ PK,
    float* __restrict__ fb1s, float* __restrict__ fb2s) {
  int bf = flags[1];
  int t0 = blockIdx.x * 256 + threadIdx.x;
  int stride = gridDim.x * 256;
  for (int i = t0; i < 10240; i += stride) {
    int j = i & 7, L = (i >> 3) & 63, t = (i >> 9) & 3, c = i >> 11;
    int k = c * 32 + ((L >> 4) << 3) + j;
    int col = t * 16 + (L & 15);
    float sc = ldf(gamma, col, bf) * rsqrtf(ldf(var, col, bf) + 1e-5f);
    float v;
    if (k < 64) v = ldf(W1_msg, k * 64 + col, bf) * sc;
    else if (k < 128) v = ldf(W1_self, (k - 64) * 64 + col, bf) * sc;
    else if (k < 144) v = ldf(W1_msg, (64 + k - 128) * 64 + col, bf) * sc;
    else if (k == 144) v = ldf(b1_msg, col, bf) * sc;
    else v = 0.0f;
    PK[i] = f2bf(v);
  }
  for (int i = t0; i < 2048; i += stride) {
    int j = i & 7, L = (i >> 3) & 63, t = (i >> 9) & 1, c = i >> 10;
    int k = c * 32 + ((L >> 4) << 3) + j;
    int col = t * 16 + (L & 15);
    PK[10240 + i] = f2bf(ldf(W2_msg, k * 32 + col, bf));
  }
  for (int i = t0; i < 3072; i += stride) {
    int j = i & 7, L = (i >> 3) & 63, t = (i >> 9) & 1, c = i >> 10;
    int k = c * 32 + ((L >> 4) << 3) + j;
    int col = t * 16 + (L & 15);
    float v;
    if (k < 64) v = ldf(W2_self, k * 32 + col, bf);
    else if (k < 80) v = ldf(W2_msg, k * 32 + col, bf);
    else if (k == 80) v = ldf(b2_msg, col, bf);
    else v = 0.0f;
    PK[12288 + i] = f2bf(v);
  }
  for (int i = t0; i < 64; i += stride) {
    float sc = ldf(gamma, i, bf) * rsqrtf(ldf(var, i, bf) + 1e-5f);
    fb1s[i] = ldf(b1_self, i, bf) * sc + ldf(beta, i, bf) - ldf(mean, i, bf) * sc;
  }
  for (int i = t0; i < 32; i += stride) fb2s[i] = ldf(b2_self, i, bf);
}

// ---------------- phase 1: LDS-staged binning by dst/391 ----------------
__global__ __launch_bounds__(256) void k_bin(const void* __restrict__ ei,
                                             const int* __restrict__ flags,
                                             int* __restrict__ bcur,
                                             int2* __restrict__ binbuf) {
  __shared__ int2 stage[NBK][SCAP];  // 57.3 KB
  __shared__ int scnt[NBK];
  __shared__ int gbase[NBK];
  int tid = threadIdx.x;
  for (int i = tid; i < NBK; i += 256) scnt[i] = 0;
  __syncthreads();
  int i64 = flags[0];
  for (long long e0 = (long long)blockIdx.x * 256; e0 < NE;
       e0 += (long long)gridDim.x * 256) {
    long long e = e0 + tid;
    if (e < NE) {
      int src = ldidx(ei, e, i64);
      int dst = ldidx(ei, NE + e, i64);
      int b = dst / BNODE;
      int dl = dst - b * BNODE;
      int2 ent = make_int2(src | (dl << 16), (int)e);
      int pos = atomicAdd(&scnt[b], 1);
      if (pos < SCAP) {
        stage[b][pos] = ent;
      } else {  // rare overflow: direct global placement
        int gp = atomicAdd(&bcur[b], 1);
        binbuf[(long long)b * BCAP + gp] = ent;
      }
    }
  }
  __syncthreads();
  if (tid < NBK) {
    int cb = scnt[tid] < SCAP ? scnt[tid] : SCAP;
    gbase[tid] = atomicAdd(&bcur[tid], cb);
  }
  __syncthreads();
  for (int b = 0; b < NBK; ++b) {
    int cb = scnt[b] < SCAP ? scnt[b] : SCAP;
    for (int i = tid; i < cb; i += 256)
      binbuf[(long long)b * BCAP + gbase[b] + i] = stage[b][i];
  }
}

// ---------------- bucket-offset scan: exclusive scan of bcur[0..128) -> bo ----------------
// (bucket totals ARE bcur — the old counts/scanA/scanB/scanC pipeline was redundant)
__global__ void k_scan128(const int* __restrict__ bcur, int* __restrict__ bo) {
  __shared__ int s[NBK];
  int t = threadIdx.x;  // 128 threads
  int orig = bcur[t];
  s[t] = orig;
  __syncthreads();
  for (int off = 1; off < NBK; off <<= 1) {
    int u = (t >= off) ? s[t - off] : 0;
    __syncthreads();
    s[t] += u;
    __syncthreads();
  }
  bo[t] = s[t] - orig;
}

// ---------------- phase 2: histogram + scan + row_ptr + placement, one kernel ----------------
__global__ __launch_bounds__(256) void k_place(const int* __restrict__ bcur,
                                               const int2* __restrict__ binbuf,
                                               const int* __restrict__ bo,
                                               int* __restrict__ row_ptr,
                                               int2* __restrict__ recs) {
  __shared__ int2 outb[BCAP];  // 60 KB
  __shared__ int lh[BNODE];
  __shared__ int lexc[BNODE];
  __shared__ int lcur[BNODE];
  int b = blockIdx.x;
  int tid = threadIdx.x;
  int base = b * BNODE;
  int nn = NN - base < BNODE ? NN - base : BNODE;
  int cnt = bcur[b];
  int rbase = bo[b];
  for (int i = tid; i < BNODE; i += 256) lh[i] = 0;
  __syncthreads();
  // pass 1: local degree histogram
  for (int i = tid; i < cnt; i += 256) {
    int dl = (binbuf[(long long)b * BCAP + i].x >> 16) & 0x3FF;
    atomicAdd(&lh[dl], 1);
  }
  __syncthreads();
  // wave-0 exclusive scan of lh[0..nn) -> lexc (7 chunks of 64 via shfl)
  if (tid < 64) {
    int carry = 0;
    for (int c0 = 0; c0 < BNODE; c0 += 64) {
      int i = c0 + tid;
      int orig = (i < nn) ? lh[i] : 0;
      int v = orig;
      for (int off = 1; off < 64; off <<= 1) {
        int u = __shfl_up(v, off, 64);
        if (tid >= off) v += u;
      }
      if (i < nn) lexc[i] = carry + v - orig;
      carry += __shfl(v, 63, 64);
    }
  }
  __syncthreads();
  // write row_ptr for this bucket; init placement cursors
  for (int i = tid; i < nn; i += 256) {
    int e = lexc[i];
    row_ptr[base + i] = rbase + e;
    lcur[i] = e;
  }
  if (b == NBK - 1 && tid == 0) row_ptr[NN] = rbase + cnt;
  __syncthreads();
  // pass 2: placement into LDS at final local offsets
  for (int i = tid; i < cnt; i += 256) {
    int2 ent = binbuf[(long long)b * BCAP + i];
    int dl = (ent.x >> 16) & 0x3FF;
    int p = atomicAdd(&lcur[dl], 1);
    outb[p] = make_int2(ent.x & 0xFFFF, ent.y);
  }
  __syncthreads();
  // flush: coalesced write of sorted records
  for (int i = tid; i < cnt; i += 256) recs[rbase + i] = outb[i];
}

// ---------------- gather 1: 8 lanes/node, unroll-4 (round-2 exact; local optimum) ----------------
// Measured floor 58 µs @ 2.85 TB/s — random-128B access-pattern roofline (~50% of
// streaming BW on 256B DRAM granules). prefetch/NT/16-lane/unroll-8/perm all regressed.
__global__ __launch_bounds__(256) void k_gather1(
    const void* __restrict__ x, const void* __restrict__ ea,
    const int* __restrict__ row_ptr, const int2* __restrict__ recs,
    const int* __restrict__ flags, unsigned short* __restrict__ F1,
    unsigned short* __restrict__ F2) {
  int lane = threadIdx.x & 63;
  int g = lane >> 3, c = lane & 7;
  int bf = flags[1];
  long long wid = ((long long)blockIdx.x * blockDim.x + threadIdx.x) >> 6;
  long long nw = ((long long)gridDim.x * blockDim.x) >> 6;
  for (long long b = wid; b < NB; b += nw) {
    int n = (int)(b * 8 + g);
    int beg = row_ptr[n];
    int deg = row_ptr[n + 1] - beg;
    float a0 = 0.f, a1 = 0.f, a2 = 0.f, a3 = 0.f, a4 = 0.f, a5 = 0.f, a6 = 0.f, a7 = 0.f;
    float e0 = 0.f, e1 = 0.f, e2 = 0.f, e3 = 0.f;
    uint4 xw;
    if (bf) {
      const unsigned short* xs = (const unsigned short*)x;
      const unsigned short* es = (const unsigned short*)ea;
      int t = 0;
      for (; t + 4 <= deg; t += 4) {
        int2 r0 = recs[beg + t + 0];
        int2 r1 = recs[beg + t + 1];
        int2 r2 = recs[beg + t + 2];
        int2 r3 = recs[beg + t + 3];
        uint4 w0 = *((const uint4*)(xs + ((long long)r0.x << 6)) + c);
        uint4 w1 = *((const uint4*)(xs + ((long long)r1.x << 6)) + c);
        uint4 w2 = *((const uint4*)(xs + ((long long)r2.x << 6)) + c);
        uint4 w3 = *((const uint4*)(xs + ((long long)r3.x << 6)) + c);
        a0 += bflo(w0.x) + bflo(w1.x) + bflo(w2.x) + bflo(w3.x);
        a1 += bfhi(w0.x) + bfhi(w1.x) + bfhi(w2.x) + bfhi(w3.x);
        a2 += bflo(w0.y) + bflo(w1.y) + bflo(w2.y) + bflo(w3.y);
        a3 += bfhi(w0.y) + bfhi(w1.y) + bfhi(w2.y) + bfhi(w3.y);
        a4 += bflo(w0.z) + bflo(w1.z) + bflo(w2.z) + bflo(w3.z);
        a5 += bfhi(w0.z) + bfhi(w1.z) + bfhi(w2.z) + bfhi(w3.z);
        a6 += bflo(w0.w) + bflo(w1.w) + bflo(w2.w) + bflo(w3.w);
        a7 += bfhi(w0.w) + bfhi(w1.w) + bfhi(w2.w) + bfhi(w3.w);
        if (c < 4) {
          uint2 q0 = *((const uint2*)(es + ((long long)r0.y << 4)) + c);
          uint2 q1 = *((const uint2*)(es + ((long long)r1.y << 4)) + c);
          uint2 q2 = *((const uint2*)(es + ((long long)r2.y << 4)) + c);
          uint2 q3 = *((const uint2*)(es + ((long long)r3.y << 4)) + c);
          e0 += bflo(q0.x) + bflo(q1.x) + bflo(q2.x) + bflo(q3.x);
          e1 += bfhi(q0.x) + bfhi(q1.x) + bfhi(q2.x) + bfhi(q3.x);
          e2 += bflo(q0.y) + bflo(q1.y) + bflo(q2.y) + bflo(q3.y);
          e3 += bfhi(q0.y) + bfhi(q1.y) + bfhi(q2.y) + bfhi(q3.y);
        }
      }
      for (; t < deg; ++t) {
        int2 r = recs[beg + t];
        uint4 w = *((const uint4*)(xs + ((long long)r.x << 6)) + c);
        a0 += bflo(w.x); a1 += bfhi(w.x);
        a2 += bflo(w.y); a3 += bfhi(w.y);
        a4 += bflo(w.z); a5 += bfhi(w.z);
        a6 += bflo(w.w); a7 += bfhi(w.w);
        if (c < 4) {
          uint2 q = *((const uint2*)(es + ((long long)r.y << 4)) + c);
          e0 += bflo(q.x); e1 += bfhi(q.x);
          e2 += bflo(q.y); e3 += bfhi(q.y);
        }
      }
      xw = *((const uint4*)(xs + ((long long)n << 6)) + c);
    } else {
      const float* xf = (const float*)x;
      const float* ef = (const float*)ea;
      for (int t = 0; t < deg; ++t) {
        int2 r = recs[beg + t];
        float4 w0 = *((const float4*)(xf + ((long long)r.x << 6)) + c * 2);
        float4 w1 = *((const float4*)(xf + ((long long)r.x << 6)) + c * 2 + 1);
        a0 += w0.x; a1 += w0.y; a2 += w0.z; a3 += w0.w;
        a4 += w1.x; a5 += w1.y; a6 += w1.z; a7 += w1.w;
        if (c < 4) {
          float4 q = *((const float4*)(ef + ((long long)r.y << 4)) + c);
          e0 += q.x; e1 += q.y; e2 += q.z; e3 += q.w;
        }
      }
      float4 p0 = *((const float4*)(xf + ((long long)n << 6)) + c * 2);
      float4 p1 = *((const float4*)(xf + ((long long)n << 6)) + c * 2 + 1);
      xw = make_uint4(pk2(p0.x, p0.y), pk2(p0.z, p0.w), pk2(p1.x, p1.y), pk2(p1.z, p1.w));
    }
    unsigned short* f1 = F1 + (long long)n * 160;
    unsigned short* f2 = F2 + (long long)n * 96;
    *((uint4*)f1 + c) = make_uint4(pk2(a0, a1), pk2(a2, a3), pk2(a4, a5), pk2(a6, a7));
    *((uint4*)(f1 + 64) + c) = xw;
    if (c < 4) {
      uint2 sp = make_uint2(pk2(e0, e1), pk2(e2, e3));
      *((uint2*)(f1 + 128) + c) = sp;
      *((uint2*)(f2 + 64) + c) = sp;
    }
    if (c == 4) {
      unsigned d = (unsigned)f2bf((float)deg);
      *((uint4*)(f1 + 144)) = make_uint4(d, 0u, 0u, 0u);
      *((uint4*)(f2 + 80)) = make_uint4(d, 0u, 0u, 0u);
    }
    if (c == 5) {
      *((uint4*)(f1 + 152)) = make_uint4(0u, 0u, 0u, 0u);
      *((uint4*)(f2 + 88)) = make_uint4(0u, 0u, 0u, 0u);
    }
  }
}

// ---------------- gemm 1 (MFMA): F1@B1 + bias -> ReLU -> F2[0..64) ; fused Y2 = h@BY ----------------
__global__ __launch_bounds__(256) void k_gemm1(
    const unsigned short* __restrict__ F1, const unsigned short* __restrict__ PK,
    const float* __restrict__ fb1s, unsigned short* __restrict__ F2,
    unsigned short* __restrict__ Y2B) {
  // per-wave LDS staging for the h-tile transpose (stride 72 shorts = conflict-light)
  __shared__ unsigned short hsh[4][16 * 72];
  int lane = threadIdx.x & 63;
  int wv = threadIdx.x >> 6;
  int m = lane & 15, quad = lane >> 4;
  unsigned short* hs = hsh[wv];
  short8x Bf[20];
#pragma unroll
  for (int s = 0; s < 20; ++s) Bf[s] = *(const short8x*)(PK + (s * 64 + lane) * 8);
  short8x By[4];
#pragma unroll
  for (int s = 0; s < 4; ++s) By[s] = *(const short8x*)(PK + 10240 + (s * 64 + lane) * 8);
  long long gw = (long long)blockIdx.x * 4 + wv;
  long long nw = (long long)gridDim.x * 4;
  for (long long tile = gw; tile < NT; tile += nw) {
    long long n0 = tile * 16;
    const unsigned short* f1 = F1 + (n0 + m) * 160 + quad * 8;
    short8x A[5];
#pragma unroll
    for (int cc = 0; cc < 5; ++cc) A[cc] = *(const short8x*)(f1 + cc * 32);
    f32x4 acc[4];
#pragma unroll
    for (int t = 0; t < 4; ++t) {
      float b = fb1s[t * 16 + m];
      acc[t] = (f32x4){b, b, b, b};
    }
#pragma unroll
    for (int cc = 0; cc < 5; ++cc) {
#pragma unroll
      for (int t = 0; t < 4; ++t)
        acc[t] = __builtin_amdgcn_mfma_f32_16x16x32_bf16(A[cc], Bf[cc * 4 + t], acc[t], 0, 0, 0);
    }
    // write h to F2 (plain, stays in L2 for gemm2) and stage bf16-rounded h in LDS
#pragma unroll
    for (int t = 0; t < 4; ++t) {
#pragma unroll
      for (int i = 0; i < 4; ++i) {
        float h = fmaxf(acc[t][i], 0.0f);
        unsigned short us = f2bf(h);
        F2[(n0 + quad * 4 + i) * 96 + t * 16 + m] = us;
        hs[(quad * 4 + i) * 72 + t * 16 + m] = us;
      }
    }
    __builtin_amdgcn_sched_barrier(0);  // keep ds_reads after ds_writes (wave-synchronous)
    f32x4 yacc[2];
    yacc[0] = (f32x4){0.f, 0.f, 0.f, 0.f};
    yacc[1] = (f32x4){0.f, 0.f, 0.f, 0.f};
#pragma unroll
    for (int cc = 0; cc < 2; ++cc) {
      short8x Ah = *(const short8x*)(hs + m * 72 + cc * 32 + quad * 8);
#pragma unroll
      for (int t = 0; t < 2; ++t)
        yacc[t] = __builtin_amdgcn_mfma_f32_16x16x32_bf16(Ah, By[cc * 2 + t], yacc[t], 0, 0, 0);
    }
#pragma unroll
    for (int t = 0; t < 2; ++t) {
#pragma unroll
      for (int i = 0; i < 4; ++i)
        Y2B[(n0 + quad * 4 + i) * 32 + t * 16 + m] = f2bf(yacc[t][i]);
    }
    __builtin_amdgcn_sched_barrier(0);
  }
}

// ---------------- gather 2: 8 lanes/node, unroll-4 (round-2 exact) ----------------
__global__ __launch_bounds__(256) void k_gather2(
    const unsigned short* __restrict__ Y2B, const int* __restrict__ row_ptr,
    const int2* __restrict__ recs, float* __restrict__ S2) {
  int lane = threadIdx.x & 63;
  int g = lane >> 3, c = lane & 7;
  long long wid = ((long long)blockIdx.x * blockDim.x + threadIdx.x) >> 6;
  long long nw = ((long long)gridDim.x * blockDim.x) >> 6;
  for (long long b = wid; b < NB; b += nw) {
    int n = (int)(b * 8 + g);
    int beg = row_ptr[n];
    int deg = row_ptr[n + 1] - beg;
    float s0 = 0.f, s1 = 0.f, s2 = 0.f, s3 = 0.f;
    int t = 0;
    for (; t + 4 <= deg; t += 4) {
      int2 r0 = recs[beg + t + 0];
      int2 r1 = recs[beg + t + 1];
      int2 r2 = recs[beg + t + 2];
      int2 r3 = recs[beg + t + 3];
      uint2 q0 = *((const uint2*)(Y2B + (long long)r0.x * 32) + c);
      uint2 q1 = *((const uint2*)(Y2B + (long long)r1.x * 32) + c);
      uint2 q2 = *((const uint2*)(Y2B + (long long)r2.x * 32) + c);
      uint2 q3 = *((const uint2*)(Y2B + (long long)r3.x * 32) + c);
      s0 += bflo(q0.x) + bflo(q1.x) + bflo(q2.x) + bflo(q3.x);
      s1 += bfhi(q0.x) + bfhi(q1.x) + bfhi(q2.x) + bfhi(q3.x);
      s2 += bflo(q0.y) + bflo(q1.y) + bflo(q2.y) + bflo(q3.y);
      s3 += bfhi(q0.y) + bfhi(q1.y) + bfhi(q2.y) + bfhi(q3.y);
    }
    for (; t < deg; ++t) {
      int2 r = recs[beg + t];
      uint2 q = *((const uint2*)(Y2B + (long long)r.x * 32) + c);
      s0 += bflo(q.x); s1 += bfhi(q.x);
      s2 += bflo(q.y); s3 += bfhi(q.y);
    }
    *(float4*)(S2 + (long long)n * 32 + c * 4) = make_float4(s0, s1, s2, s3);
  }
}

// ---------------- gemm 2 (MFMA): F2@B2 + S2 + fb2s -> out ----------------
__global__ __launch_bounds__(256) void k_gemm2(
    const unsigned short* __restrict__ F2, const unsigned short* __restrict__ PK,
    const float* __restrict__ fb2s, const float* __restrict__ S2,
    const int* __restrict__ flags, void* __restrict__ out) {
  int lane = threadIdx.x & 63;
  int wv = threadIdx.x >> 6;
  int m = lane & 15, quad = lane >> 4;
  int bf = flags[1];
  short8x Bf[6];
#pragma unroll
  for (int s = 0; s < 6; ++s) Bf[s] = *(const short8x*)(PK + 12288 + (s * 64 + lane) * 8);
  long long gw = (long long)blockIdx.x * 4 + wv;
  long long nw = (long long)gridDim.x * 4;
  for (long long tile = gw; tile < NT; tile += nw) {
    long long n0 = tile * 16;
    const unsigned short* f2 = F2 + (n0 + m) * 96 + quad * 8;
    short8x A[3];
#pragma unroll
    for (int cc = 0; cc < 3; ++cc) A[cc] = *(const short8x*)(f2 + cc * 32);
    f32x4 acc[2];
#pragma unroll
    for (int t = 0; t < 2; ++t) {
      float b = fb2s[t * 16 + m];
#pragma unroll
      for (int i = 0; i < 4; ++i)
        acc[t][i] = b + S2[(n0 + quad * 4 + i) * 32 + t * 16 + m];
    }
#pragma unroll
    for (int cc = 0; cc < 3; ++cc) {
#pragma unroll
      for (int t = 0; t < 2; ++t)
        acc[t] = __builtin_amdgcn_mfma_f32_16x16x32_bf16(A[cc], Bf[cc * 2 + t], acc[t], 0, 0, 0);
    }
#pragma unroll
    for (int t = 0; t < 2; ++t) {
#pragma unroll
      for (int i = 0; i < 4; ++i) {
        long long idx = (n0 + quad * 4 + i) * 32 + t * 16 + m;
        if (bf) ((unsigned short*)out)[idx] = f2bf(acc[t][i]);
        else ((float*)out)[idx] = acc[t][i];
      }
    }
  }
}

extern "C" void kernel_launch(void* const* d_in, const int* in_sizes, int n_in,
                              void* d_out, int out_size, void* d_ws, size_t ws_size,
                              hipStream_t stream) {
  const void* x = d_in[0];
  const void* ei = d_in[1];
  const void* ea = d_in[2];
  const void* W1_msg = d_in[3];
  const void* b1_msg = d_in[4];
  const void* W1_self = d_in[5];
  const void* b1_self = d_in[6];
  const void* gamma = d_in[7];
  const void* beta = d_in[8];
  const void* mean = d_in[9];
  const void* var = d_in[10];
  const void* W2_msg = d_in[11];
  const void* b2_msg = d_in[12];
  const void* W2_self = d_in[13];
  const void* b2_self = d_in[14];

  float* ws = (float*)d_ws;
  int* row_ptr = (int*)(ws + OFF_ROW);
  int2* recs = (int2*)(ws + OFF_RECS);
  int* flags = (int*)(ws + OFF_FLAGS);
  int* bo = (int*)(ws + OFF_BO);
  unsigned short* PK = (unsigned short*)(ws + OFF_PK);
  float* fb1s = ws + OFF_FB1S;
  float* fb2s = ws + OFF_FB2S;
  unsigned short* F1 = (unsigned short*)(ws + OFF_F1);
  int2* binbuf = (int2*)(ws + OFF_F1);  // aliases F1 (dead before gather1)
  unsigned short* F2 = (unsigned short*)(ws + OFF_F2);
  unsigned short* Y2B = (unsigned short*)(ws + OFF_Y2B);
  float* S2 = ws + OFF_S2;
  int* bcur = (int*)(ws + OFF_BCUR);

  hipLaunchKernelGGL(k_detect, dim3(1), dim3(64), 0, stream, ei, x, flags);
  hipMemsetAsync(bcur, 0, NBK * sizeof(int), stream);
  hipLaunchKernelGGL(k_prep, dim3(64), dim3(256), 0, stream, W1_msg, b1_msg, W1_self,
                     b1_self, gamma, beta, mean, var, W2_msg, b2_msg, W2_self, b2_self,
                     flags, PK, fb1s, fb2s);

  hipLaunchKernelGGL(k_bin, dim3(256), dim3(256), 0, stream, ei, flags, bcur, binbuf);
  hipLaunchKernelGGL(k_scan128, dim3(1), dim3(NBK), 0, stream, bcur, bo);
  hipLaunchKernelGGL(k_place, dim3(NBK), dim3(256), 0, stream, bcur, binbuf, bo,
                     row_ptr, recs);

  int gblocks = (NB + 3) / 4;
  hipLaunchKernelGGL(k_gather1, dim3(gblocks), dim3(256), 0, stream, x, ea, row_ptr,
                     recs, flags, F1, F2);
  int mblocks = (NT + 3) / 4;
  hipLaunchKernelGGL(k_gemm1, dim3(mblocks), dim3(256), 0, stream, F1, PK, fb1s, F2,
                     Y2B);
  hipLaunchKernelGGL(k_gather2, dim3(gblocks), dim3(256), 0, stream, Y2B, row_ptr, recs,
                     S2);
  hipLaunchKernelGGL(k_gemm2, dim3(mblocks), dim3(256), 0, stream, F2, PK, fb2s, S2,
                     flags, d_out);
}

// Round 8
// 223.500 us; speedup vs baseline: 1.1922x; 1.0802x over previous
//
#include <hip/hip_runtime.h>

#define NN 50000
#define NE 800000
#define NB 6250        // NN/8 gather batches
#define NT 3125        // NN/16 mfma tiles
#define NBK 128        // coarse buckets
#define BNODE 391      // nodes per bucket (391*128 = 50048 >= NN)
#define BCAP 7680      // bucket capacity (mean 6250, +18 sigma)
#define SCAP 56        // per-block LDS stage capacity per bucket

typedef __attribute__((ext_vector_type(8))) short short8x;
typedef __attribute__((ext_vector_type(4))) float f32x4;

// ws layout (float-index offsets)
#define OFF_CNT   0LL                 // NN ints (unused, layout stability)
#define OFF_ROW   ((long long)NN)     // NN+1 ints (row_ptr)
#define OFF_RECS  (3LL*NN + 16)       // NE int2
#define OFF_FLAGS (35LL*NN + 16)      // ints
#define OFF_BO    (35LL*NN + 96)      // 128 ints (unused)
#define OFF_PK    (35LL*NN + 256)     // 15360 ushorts (16B-aligned)
#define OFF_FB1S  (35LL*NN + 7936)    // 64 f32
#define OFF_FB2S  (35LL*NN + 8000)    // 32 f32
#define OFF_F1    (36LL*NN)           // NN*160 bf16  (binbuf aliases this region)
#define OFF_F2    (116LL*NN)          // NN*96 bf16
#define OFF_Y2B   (164LL*NN)          // NN*32 bf16
#define OFF_S2    (180LL*NN)          // NN*32 f32
#define OFF_BCUR  (212LL*NN)          // 128 ints

__device__ __forceinline__ float ldf(const void* p, long long i, int bf16) {
  if (bf16) {
    unsigned short u = ((const unsigned short*)p)[i];
    return __uint_as_float(((unsigned)u) << 16);
  }
  return ((const float*)p)[i];
}
__device__ __forceinline__ unsigned short f2bf(float f) {
  unsigned u = __float_as_uint(f);
  unsigned r = (u + 0x7fffu + ((u >> 16) & 1u)) >> 16;
  return (unsigned short)r;
}
__device__ __forceinline__ unsigned pk2(float lo, float hi) {
  return (unsigned)f2bf(lo) | ((unsigned)f2bf(hi) << 16);
}
__device__ __forceinline__ int ldidx(const void* p, long long i, int i64) {
  return i64 ? (int)((const long long*)p)[i] : ((const int*)p)[i];
}
__device__ __forceinline__ float bflo(unsigned u) { return __uint_as_float(u << 16); }
__device__ __forceinline__ float bfhi(unsigned u) { return __uint_as_float(u & 0xffff0000u); }

// ---------------- pack BN-folded weights; block 0 also publishes dtype flags ----------------
__global__ __launch_bounds__(256) void k_prep(
    const void* __restrict__ ei, const void* __restrict__ x,
    const void* __restrict__ W1_msg, const void* __restrict__ b1_msg,
    const void* __restrict__ W1_self, const void* __restrict__ b1_self,
    const void* __restrict__ gamma, const void* __restrict__ beta,
    const void* __restrict__ mean, const void* __restrict__ var,
    const void* __restrict__ W2_msg, const void* __restrict__ b2_msg,
    const void* __restrict__ W2_self, const void* __restrict__ b2_self,
    int* __restrict__ flags, unsigned short* __restrict__ PK,
    float* __restrict__ fb1s, float* __restrict__ fb2s) {
  __shared__ int s_bf;
  int tid = threadIdx.x;
  int lane = tid & 63;
  // every block computes bf locally (cheap); block 0 publishes flags for later kernels
  if (tid < 64) {
    const unsigned short* q = (const unsigned short*)x;
    int cntc = 0;
    for (int i = lane; i < 256; i += 64) {
      unsigned short w = q[2 * i];
      int e = (w >> 7) & 0xff;
      if (w == 0 || (e >= 110 && e <= 140)) cntc++;
    }
    for (int m = 1; m < 64; m <<= 1) cntc += __shfl_xor(cntc, m, 64);
    int bfv = (cntc >= 192) ? 1 : 0;
    if (blockIdx.x == 0) {
      const int* p = (const int*)ei;
      int any = 0;
      for (int i = lane; i < 256; i += 64) any |= p[2 * i + 1];
      unsigned long long anyb = __ballot(any != 0);
      if (lane == 0) {
        flags[0] = (anyb == 0ull) ? 1 : 0;
        flags[1] = bfv;
      }
    }
    if (lane == 0) s_bf = bfv;
  }
  __syncthreads();
  int bf = s_bf;
  int t0 = blockIdx.x * 256 + tid;
  int stride = gridDim.x * 256;
  for (int i = t0; i < 10240; i += stride) {
    int j = i & 7, L = (i >> 3) & 63, t = (i >> 9) & 3, c = i >> 11;
    int k = c * 32 + ((L >> 4) << 3) + j;
    int col = t * 16 + (L & 15);
    float sc = ldf(gamma, col, bf) * rsqrtf(ldf(var, col, bf) + 1e-5f);
    float v;
    if (k < 64) v = ldf(W1_msg, k * 64 + col, bf) * sc;
    else if (k < 128) v = ldf(W1_self, (k - 64) * 64 + col, bf) * sc;
    else if (k < 144) v = ldf(W1_msg, (64 + k - 128) * 64 + col, bf) * sc;
    else if (k == 144) v = ldf(b1_msg, col, bf) * sc;
    else v = 0.0f;
    PK[i] = f2bf(v);
  }
  for (int i = t0; i < 2048; i += stride) {
    int j = i & 7, L = (i >> 3) & 63, t = (i >> 9) & 1, c = i >> 10;
    int k = c * 32 + ((L >> 4) << 3) + j;
    int col = t * 16 + (L & 15);
    PK[10240 + i] = f2bf(ldf(W2_msg, k * 32 + col, bf));
  }
  for (int i = t0; i < 3072; i += stride) {
    int j = i & 7, L = (i >> 3) & 63, t = (i >> 9) & 1, c = i >> 10;
    int k = c * 32 + ((L >> 4) << 3) + j;
    int col = t * 16 + (L & 15);
    float v;
    if (k < 64) v = ldf(W2_self, k * 32 + col, bf);
    else if (k < 80) v = ldf(W2_msg, k * 32 + col, bf);
    else if (k == 80) v = ldf(b2_msg, col, bf);
    else v = 0.0f;
    PK[12288 + i] = f2bf(v);
  }
  for (int i = t0; i < 64; i += stride) {
    float sc = ldf(gamma, i, bf) * rsqrtf(ldf(var, i, bf) + 1e-5f);
    fb1s[i] = ldf(b1_self, i, bf) * sc + ldf(beta, i, bf) - ldf(mean, i, bf) * sc;
  }
  for (int i = t0; i < 32; i += stride) fb2s[i] = ldf(b2_self, i, bf);
}

// ---------------- phase 1: LDS-staged binning by dst/391 ----------------
__global__ __launch_bounds__(256) void k_bin(const void* __restrict__ ei,
                                             const int* __restrict__ flags,
                                             int* __restrict__ bcur,
                                             int2* __restrict__ binbuf) {
  __shared__ int2 stage[NBK][SCAP];  // 57.3 KB
  __shared__ int scnt[NBK];
  __shared__ int gbase[NBK];
  int tid = threadIdx.x;
  for (int i = tid; i < NBK; i += 256) scnt[i] = 0;
  __syncthreads();
  int i64 = flags[0];
  for (long long e0 = (long long)blockIdx.x * 256; e0 < NE;
       e0 += (long long)gridDim.x * 256) {
    long long e = e0 + tid;
    if (e < NE) {
      int src = ldidx(ei, e, i64);
      int dst = ldidx(ei, NE + e, i64);
      int b = dst / BNODE;
      int dl = dst - b * BNODE;
      int2 ent = make_int2(src | (dl << 16), (int)e);
      int pos = atomicAdd(&scnt[b], 1);
      if (pos < SCAP) {
        stage[b][pos] = ent;
      } else {  // rare overflow: direct global placement
        int gp = atomicAdd(&bcur[b], 1);
        binbuf[(long long)b * BCAP + gp] = ent;
      }
    }
  }
  __syncthreads();
  if (tid < NBK) {
    int cb = scnt[tid] < SCAP ? scnt[tid] : SCAP;
    gbase[tid] = atomicAdd(&bcur[tid], cb);
  }
  __syncthreads();
  // flush parallelized across the 4 waves (was a 128-iteration serial block loop)
  int wv = tid >> 6, ln = tid & 63;
  for (int b = wv; b < NBK; b += 4) {
    int cb = scnt[b] < SCAP ? scnt[b] : SCAP;
    int gb = gbase[b];
    for (int i = ln; i < cb; i += 64)
      binbuf[(long long)b * BCAP + gb + i] = stage[b][i];
  }
}

// ---------------- phase 2: prefix + histogram + scan + row_ptr + placement ----------------
// 1024 threads: place launches only NBK=128 blocks (0.5/CU), so per-block speed is the lever.
__global__ __launch_bounds__(1024) void k_place(const int* __restrict__ bcur,
                                                const int2* __restrict__ binbuf,
                                                int* __restrict__ row_ptr,
                                                int2* __restrict__ recs) {
  __shared__ int2 outb[BCAP];  // 60 KB
  __shared__ int lh[BNODE];
  __shared__ int lexc[BNODE];
  __shared__ int lcur[BNODE];
  __shared__ int sb[NBK];
  __shared__ int s_rbase;
  int b = blockIdx.x;
  int tid = threadIdx.x;
  int base = b * BNODE;
  int nn = NN - base < BNODE ? NN - base : BNODE;
  if (tid < NBK) sb[tid] = bcur[tid];
  for (int i = tid; i < BNODE; i += 1024) lh[i] = 0;
  __syncthreads();
  // rbase = exclusive prefix of bucket totals (bcur IS the per-bucket edge count)
  if (tid < 64) {
    int v = (tid < b ? sb[tid] : 0) + (tid + 64 < b ? sb[tid + 64] : 0);
    for (int off = 32; off > 0; off >>= 1) v += __shfl_down(v, off, 64);
    if (tid == 0) s_rbase = v;
  }
  int cnt = sb[b];
  __syncthreads();
  int rbase = s_rbase;
  // pass 1: local degree histogram
  for (int i = tid; i < cnt; i += 1024) {
    int dl = (binbuf[(long long)b * BCAP + i].x >> 16) & 0x3FF;
    atomicAdd(&lh[dl], 1);
  }
  __syncthreads();
  // wave-0 exclusive scan of lh[0..nn) -> lexc (7 chunks of 64 via shfl)
  if (tid < 64) {
    int carry = 0;
    for (int c0 = 0; c0 < BNODE; c0 += 64) {
      int i = c0 + tid;
      int orig = (i < nn) ? lh[i] : 0;
      int v = orig;
      for (int off = 1; off < 64; off <<= 1) {
        int u = __shfl_up(v, off, 64);
        if (tid >= off) v += u;
      }
      if (i < nn) lexc[i] = carry + v - orig;
      carry += __shfl(v, 63, 64);
    }
  }
  __syncthreads();
  // write row_ptr for this bucket; init placement cursors
  for (int i = tid; i < nn; i += 1024) {
    int e = lexc[i];
    row_ptr[base + i] = rbase + e;
    lcur[i] = e;
  }
  if (b == NBK - 1 && tid == 0) row_ptr[NN] = rbase + cnt;
  __syncthreads();
  // pass 2: placement into LDS at final local offsets
  for (int i = tid; i < cnt; i += 1024) {
    int2 ent = binbuf[(long long)b * BCAP + i];
    int dl = (ent.x >> 16) & 0x3FF;
    int p = atomicAdd(&lcur[dl], 1);
    outb[p] = make_int2(ent.x & 0xFFFF, ent.y);
  }
  __syncthreads();
  // flush: coalesced write of sorted records
  for (int i = tid; i < cnt; i += 1024) recs[rbase + i] = outb[i];
}

// ---------------- gather 1: 8 lanes/node, unroll-4 (round-2 exact; local optimum) ----------------
// Measured floor 58 µs @ 2.85 TB/s — random-128B access-pattern roofline (~50% of
// streaming BW on 256B DRAM granules). prefetch/NT/16-lane/unroll-8/perm all regressed.
__global__ __launch_bounds__(256) void k_gather1(
    const void* __restrict__ x, const void* __restrict__ ea,
    const int* __restrict__ row_ptr, const int2* __restrict__ recs,
    const int* __restrict__ flags, unsigned short* __restrict__ F1,
    unsigned short* __restrict__ F2) {
  int lane = threadIdx.x & 63;
  int g = lane >> 3, c = lane & 7;
  int bf = flags[1];
  long long wid = ((long long)blockIdx.x * blockDim.x + threadIdx.x) >> 6;
  long long nw = ((long long)gridDim.x * blockDim.x) >> 6;
  for (long long b = wid; b < NB; b += nw) {
    int n = (int)(b * 8 + g);
    int beg = row_ptr[n];
    int deg = row_ptr[n + 1] - beg;
    float a0 = 0.f, a1 = 0.f, a2 = 0.f, a3 = 0.f, a4 = 0.f, a5 = 0.f, a6 = 0.f, a7 = 0.f;
    float e0 = 0.f, e1 = 0.f, e2 = 0.f, e3 = 0.f;
    uint4 xw;
    if (bf) {
      const unsigned short* xs = (const unsigned short*)x;
      const unsigned short* es = (const unsigned short*)ea;
      int t = 0;
      for (; t + 4 <= deg; t += 4) {
        int2 r0 = recs[beg + t + 0];
        int2 r1 = recs[beg + t + 1];
        int2 r2 = recs[beg + t + 2];
        int2 r3 = recs[beg + t + 3];
        uint4 w0 = *((const uint4*)(xs + ((long long)r0.x << 6)) + c);
        uint4 w1 = *((const uint4*)(xs + ((long long)r1.x << 6)) + c);
        uint4 w2 = *((const uint4*)(xs + ((long long)r2.x << 6)) + c);
        uint4 w3 = *((const uint4*)(xs + ((long long)r3.x << 6)) + c);
        a0 += bflo(w0.x) + bflo(w1.x) + bflo(w2.x) + bflo(w3.x);
        a1 += bfhi(w0.x) + bfhi(w1.x) + bfhi(w2.x) + bfhi(w3.x);
        a2 += bflo(w0.y) + bflo(w1.y) + bflo(w2.y) + bflo(w3.y);
        a3 += bfhi(w0.y) + bfhi(w1.y) + bfhi(w2.y) + bfhi(w3.y);
        a4 += bflo(w0.z) + bflo(w1.z) + bflo(w2.z) + bflo(w3.z);
        a5 += bfhi(w0.z) + bfhi(w1.z) + bfhi(w2.z) + bfhi(w3.z);
        a6 += bflo(w0.w) + bflo(w1.w) + bflo(w2.w) + bflo(w3.w);
        a7 += bfhi(w0.w) + bfhi(w1.w) + bfhi(w2.w) + bfhi(w3.w);
        if (c < 4) {
          uint2 q0 = *((const uint2*)(es + ((long long)r0.y << 4)) + c);
          uint2 q1 = *((const uint2*)(es + ((long long)r1.y << 4)) + c);
          uint2 q2 = *((const uint2*)(es + ((long long)r2.y << 4)) + c);
          uint2 q3 = *((const uint2*)(es + ((long long)r3.y << 4)) + c);
          e0 += bflo(q0.x) + bflo(q1.x) + bflo(q2.x) + bflo(q3.x);
          e1 += bfhi(q0.x) + bfhi(q1.x) + bfhi(q2.x) + bfhi(q3.x);
          e2 += bflo(q0.y) + bflo(q1.y) + bflo(q2.y) + bflo(q3.y);
          e3 += bfhi(q0.y) + bfhi(q1.y) + bfhi(q2.y) + bfhi(q3.y);
        }
      }
      for (; t < deg; ++t) {
        int2 r = recs[beg + t];
        uint4 w = *((const uint4*)(xs + ((long long)r.x << 6)) + c);
        a0 += bflo(w.x); a1 += bfhi(w.x);
        a2 += bflo(w.y); a3 += bfhi(w.y);
        a4 += bflo(w.z); a5 += bfhi(w.z);
        a6 += bflo(w.w); a7 += bfhi(w.w);
        if (c < 4) {
          uint2 q = *((const uint2*)(es + ((long long)r.y << 4)) + c);
          e0 += bflo(q.x); e1 += bfhi(q.x);
          e2 += bflo(q.y); e3 += bfhi(q.y);
        }
      }
      xw = *((const uint4*)(xs + ((long long)n << 6)) + c);
    } else {
      const float* xf = (const float*)x;
      const float* ef = (const float*)ea;
      for (int t = 0; t < deg; ++t) {
        int2 r = recs[beg + t];
        float4 w0 = *((const float4*)(xf + ((long long)r.x << 6)) + c * 2);
        float4 w1 = *((const float4*)(xf + ((long long)r.x << 6)) + c * 2 + 1);
        a0 += w0.x; a1 += w0.y; a2 += w0.z; a3 += w0.w;
        a4 += w1.x; a5 += w1.y; a6 += w1.z; a7 += w1.w;
        if (c < 4) {
          float4 q = *((const float4*)(ef + ((long long)r.y << 4)) + c);
          e0 += q.x; e1 += q.y; e2 += q.z; e3 += q.w;
        }
      }
      float4 p0 = *((const float4*)(xf + ((long long)n << 6)) + c * 2);
      float4 p1 = *((const float4*)(xf + ((long long)n << 6)) + c * 2 + 1);
      xw = make_uint4(pk2(p0.x, p0.y), pk2(p0.z, p0.w), pk2(p1.x, p1.y), pk2(p1.z, p1.w));
    }
    unsigned short* f1 = F1 + (long long)n * 160;
    unsigned short* f2 = F2 + (long long)n * 96;
    *((uint4*)f1 + c) = make_uint4(pk2(a0, a1), pk2(a2, a3), pk2(a4, a5), pk2(a6, a7));
    *((uint4*)(f1 + 64) + c) = xw;
    if (c < 4) {
      uint2 sp = make_uint2(pk2(e0, e1), pk2(e2, e3));
      *((uint2*)(f1 + 128) + c) = sp;
      *((uint2*)(f2 + 64) + c) = sp;
    }
    if (c == 4) {
      unsigned d = (unsigned)f2bf((float)deg);
      *((uint4*)(f1 + 144)) = make_uint4(d, 0u, 0u, 0u);
      *((uint4*)(f2 + 80)) = make_uint4(d, 0u, 0u, 0u);
    }
    if (c == 5) {
      *((uint4*)(f1 + 152)) = make_uint4(0u, 0u, 0u, 0u);
      *((uint4*)(f2 + 88)) = make_uint4(0u, 0u, 0u, 0u);
    }
  }
}

// ---------------- gemm 1 (MFMA): F1@B1 + bias -> ReLU -> F2[0..64) ; fused Y2 = h@BY ----------------
__global__ __launch_bounds__(256) void k_gemm1(
    const unsigned short* __restrict__ F1, const unsigned short* __restrict__ PK,
    const float* __restrict__ fb1s, unsigned short* __restrict__ F2,
    unsigned short* __restrict__ Y2B) {
  // per-wave LDS staging for the h-tile transpose (stride 72 shorts = conflict-light)
  __shared__ unsigned short hsh[4][16 * 72];
  int lane = threadIdx.x & 63;
  int wv = threadIdx.x >> 6;
  int m = lane & 15, quad = lane >> 4;
  unsigned short* hs = hsh[wv];
  short8x Bf[20];
#pragma unroll
  for (int s = 0; s < 20; ++s) Bf[s] = *(const short8x*)(PK + (s * 64 + lane) * 8);
  short8x By[4];
#pragma unroll
  for (int s = 0; s < 4; ++s) By[s] = *(const short8x*)(PK + 10240 + (s * 64 + lane) * 8);
  long long gw = (long long)blockIdx.x * 4 + wv;
  long long nw = (long long)gridDim.x * 4;
  for (long long tile = gw; tile < NT; tile += nw) {
    long long n0 = tile * 16;
    const unsigned short* f1 = F1 + (n0 + m) * 160 + quad * 8;
    short8x A[5];
#pragma unroll
    for (int cc = 0; cc < 5; ++cc) A[cc] = *(const short8x*)(f1 + cc * 32);
    f32x4 acc[4];
#pragma unroll
    for (int t = 0; t < 4; ++t) {
      float b = fb1s[t * 16 + m];
      acc[t] = (f32x4){b, b, b, b};
    }
#pragma unroll
    for (int cc = 0; cc < 5; ++cc) {
#pragma unroll
      for (int t = 0; t < 4; ++t)
        acc[t] = __builtin_amdgcn_mfma_f32_16x16x32_bf16(A[cc], Bf[cc * 4 + t], acc[t], 0, 0, 0);
    }
    // write h to F2 (plain, stays in L2 for gemm2) and stage bf16-rounded h in LDS
#pragma unroll
    for (int t = 0; t < 4; ++t) {
#pragma unroll
      for (int i = 0; i < 4; ++i) {
        float h = fmaxf(acc[t][i], 0.0f);
        unsigned short us = f2bf(h);
        F2[(n0 + quad * 4 + i) * 96 + t * 16 + m] = us;
        hs[(quad * 4 + i) * 72 + t * 16 + m] = us;
      }
    }
    __builtin_amdgcn_sched_barrier(0);  // keep ds_reads after ds_writes (wave-synchronous)
    f32x4 yacc[2];
    yacc[0] = (f32x4){0.f, 0.f, 0.f, 0.f};
    yacc[1] = (f32x4){0.f, 0.f, 0.f, 0.f};
#pragma unroll
    for (int cc = 0; cc < 2; ++cc) {
      short8x Ah = *(const short8x*)(hs + m * 72 + cc * 32 + quad * 8);
#pragma unroll
      for (int t = 0; t < 2; ++t)
        yacc[t] = __builtin_amdgcn_mfma_f32_16x16x32_bf16(Ah, By[cc * 2 + t], yacc[t], 0, 0, 0);
    }
#pragma unroll
    for (int t = 0; t < 2; ++t) {
#pragma unroll
      for (int i = 0; i < 4; ++i)
        Y2B[(n0 + quad * 4 + i) * 32 + t * 16 + m] = f2bf(yacc[t][i]);
    }
    __builtin_amdgcn_sched_barrier(0);
  }
}

// ---------------- gather 2: 8 lanes/node, unroll-4 (round-2 exact) ----------------
__global__ __launch_bounds__(256) void k_gather2(
    const unsigned short* __restrict__ Y2B, const int* __restrict__ row_ptr,
    const int2* __restrict__ recs, float* __restrict__ S2) {
  int lane = threadIdx.x & 63;
  int g = lane >> 3, c = lane & 7;
  long long wid = ((long long)blockIdx.x * blockDim.x + threadIdx.x) >> 6;
  long long nw = ((long long)gridDim.x * blockDim.x) >> 6;
  for (long long b = wid; b < NB; b += nw) {
    int n = (int)(b * 8 + g);
    int beg = row_ptr[n];
    int deg = row_ptr[n + 1] - beg;
    float s0 = 0.f, s1 = 0.f, s2 = 0.f, s3 = 0.f;
    int t = 0;
    for (; t + 4 <= deg; t += 4) {
      int2 r0 = recs[beg + t + 0];
      int2 r1 = recs[beg + t + 1];
      int2 r2 = recs[beg + t + 2];
      int2 r3 = recs[beg + t + 3];
      uint2 q0 = *((const uint2*)(Y2B + (long long)r0.x * 32) + c);
      uint2 q1 = *((const uint2*)(Y2B + (long long)r1.x * 32) + c);
      uint2 q2 = *((const uint2*)(Y2B + (long long)r2.x * 32) + c);
      uint2 q3 = *((const uint2*)(Y2B + (long long)r3.x * 32) + c);
      s0 += bflo(q0.x) + bflo(q1.x) + bflo(q2.x) + bflo(q3.x);
      s1 += bfhi(q0.x) + bfhi(q1.x) + bfhi(q2.x) + bfhi(q3.x);
      s2 += bflo(q0.y) + bflo(q1.y) + bflo(q2.y) + bflo(q3.y);
      s3 += bfhi(q0.y) + bfhi(q1.y) + bfhi(q2.y) + bfhi(q3.y);
    }
    for (; t < deg; ++t) {
      int2 r = recs[beg + t];
      uint2 q = *((const uint2*)(Y2B + (long long)r.x * 32) + c);
      s0 += bflo(q.x); s1 += bfhi(q.x);
      s2 += bflo(q.y); s3 += bfhi(q.y);
    }
    *(float4*)(S2 + (long long)n * 32 + c * 4) = make_float4(s0, s1, s2, s3);
  }
}

// ---------------- gemm 2 (MFMA): F2@B2 + S2 + fb2s -> out ----------------
__global__ __launch_bounds__(256) void k_gemm2(
    const unsigned short* __restrict__ F2, const unsigned short* __restrict__ PK,
    const float* __restrict__ fb2s, const float* __restrict__ S2,
    const int* __restrict__ flags, void* __restrict__ out) {
  int lane = threadIdx.x & 63;
  int wv = threadIdx.x >> 6;
  int m = lane & 15, quad = lane >> 4;
  int bf = flags[1];
  short8x Bf[6];
#pragma unroll
  for (int s = 0; s < 6; ++s) Bf[s] = *(const short8x*)(PK + 12288 + (s * 64 + lane) * 8);
  long long gw = (long long)blockIdx.x * 4 + wv;
  long long nw = (long long)gridDim.x * 4;
  for (long long tile = gw; tile < NT; tile += nw) {
    long long n0 = tile * 16;
    const unsigned short* f2 = F2 + (n0 + m) * 96 + quad * 8;
    short8x A[3];
#pragma unroll
    for (int cc = 0; cc < 3; ++cc) A[cc] = *(const short8x*)(f2 + cc * 32);
    f32x4 acc[2];
#pragma unroll
    for (int t = 0; t < 2; ++t) {
      float b = fb2s[t * 16 + m];
#pragma unroll
      for (int i = 0; i < 4; ++i)
        acc[t][i] = b + S2[(n0 + quad * 4 + i) * 32 + t * 16 + m];
    }
#pragma unroll
    for (int cc = 0; cc < 3; ++cc) {
#pragma unroll
      for (int t = 0; t < 2; ++t)
        acc[t] = __builtin_amdgcn_mfma_f32_16x16x32_bf16(A[cc], Bf[cc * 2 + t], acc[t], 0, 0, 0);
    }
#pragma unroll
    for (int t = 0; t < 2; ++t) {
#pragma unroll
      for (int i = 0; i < 4; ++i) {
        long long idx = (n0 + quad * 4 + i) * 32 + t * 16 + m;
        if (bf) ((unsigned short*)out)[idx] = f2bf(acc[t][i]);
        else ((float*)out)[idx] = acc[t][i];
      }
    }
  }
}

extern "C" void kernel_launch(void* const* d_in, const int* in_sizes, int n_in,
                              void* d_out, int out_size, void* d_ws, size_t ws_size,
                              hipStream_t stream) {
  const void* x = d_in[0];
  const void* ei = d_in[1];
  const void* ea = d_in[2];
  const void* W1_msg = d_in[3];
  const void* b1_msg = d_in[4];
  const void* W1_self = d_in[5];
  const void* b1_self = d_in[6];
  const void* gamma = d_in[7];
  const void* beta = d_in[8];
  const void* mean = d_in[9];
  const void* var = d_in[10];
  const void* W2_msg = d_in[11];
  const void* b2_msg = d_in[12];
  const void* W2_self = d_in[13];
  const void* b2_self = d_in[14];

  float* ws = (float*)d_ws;
  int* row_ptr = (int*)(ws + OFF_ROW);
  int2* recs = (int2*)(ws + OFF_RECS);
  int* flags = (int*)(ws + OFF_FLAGS);
  unsigned short* PK = (unsigned short*)(ws + OFF_PK);
  float* fb1s = ws + OFF_FB1S;
  float* fb2s = ws + OFF_FB2S;
  unsigned short* F1 = (unsigned short*)(ws + OFF_F1);
  int2* binbuf = (int2*)(ws + OFF_F1);  // aliases F1 (dead before gather1)
  unsigned short* F2 = (unsigned short*)(ws + OFF_F2);
  unsigned short* Y2B = (unsigned short*)(ws + OFF_Y2B);
  float* S2 = ws + OFF_S2;
  int* bcur = (int*)(ws + OFF_BCUR);

  hipMemsetAsync(bcur, 0, NBK * sizeof(int), stream);
  hipLaunchKernelGGL(k_prep, dim3(64), dim3(256), 0, stream, ei, x, W1_msg, b1_msg,
                     W1_self, b1_self, gamma, beta, mean, var, W2_msg, b2_msg, W2_self,
                     b2_self, flags, PK, fb1s, fb2s);
  hipLaunchKernelGGL(k_bin, dim3(256), dim3(256), 0, stream, ei, flags, bcur, binbuf);
  hipLaunchKernelGGL(k_place, dim3(NBK), dim3(1024), 0, stream, bcur, binbuf, row_ptr,
                     recs);

  int gblocks = (NB + 3) / 4;
  hipLaunchKernelGGL(k_gather1, dim3(gblocks), dim3(256), 0, stream, x, ea, row_ptr,
                     recs, flags, F1, F2);
  int mblocks = (NT + 3) / 4;
  hipLaunchKernelGGL(k_gemm1, dim3(mblocks), dim3(256), 0, stream, F1, PK, fb1s, F2,
                     Y2B);
  hipLaunchKernelGGL(k_gather2, dim3(gblocks), dim3(256), 0, stream, Y2B, row_ptr, recs,
                     S2);
  hipLaunchKernelGGL(k_gemm2, dim3(mblocks), dim3(256), 0, stream, F2, PK, fb2s, S2,
                     flags, d_out);
}

// Round 9
// 212.322 us; speedup vs baseline: 1.2550x; 1.0526x over previous
//
#include <hip/hip_runtime.h>

#define NN 50000
#define NE 800000
#define NB 6250        // NN/8 gather batches
#define NT 3125        // NN/16 mfma tiles
#define NBK 128        // coarse buckets
#define BNODE 391      // nodes per bucket (391*128 = 50048 >= NN)
#define BCAP 7680      // bucket capacity (mean 6250, +18 sigma)
#define SCAP 56        // per-block LDS stage capacity per bucket
#define BINBLK 256     // bin-part blocks in k_prepbin
#define PREPBLK 64     // prep-part blocks in k_prepbin

typedef __attribute__((ext_vector_type(8))) short short8x;
typedef __attribute__((ext_vector_type(4))) float f32x4;

// ws layout (float-index offsets)
#define OFF_CNT   0LL                 // NN ints (unused, layout stability)
#define OFF_ROW   ((long long)NN)     // NN+1 ints (row_ptr)
#define OFF_RECS  (3LL*NN + 16)       // NE int2
#define OFF_FLAGS (35LL*NN + 16)      // ints
#define OFF_PK    (35LL*NN + 256)     // 15360 ushorts (16B-aligned)
#define OFF_FB1S  (35LL*NN + 7936)    // 64 f32
#define OFF_FB2S  (35LL*NN + 8000)    // 32 f32
#define OFF_F1    (36LL*NN)           // NN*160 bf16  (binbuf aliases this region)
#define OFF_F2    (116LL*NN)          // NN*96 bf16
#define OFF_Y2B   (164LL*NN)          // NN*32 bf16
#define OFF_BCUR  (212LL*NN)          // 128 ints

__device__ __forceinline__ float ldf(const void* p, long long i, int bf16) {
  if (bf16) {
    unsigned short u = ((const unsigned short*)p)[i];
    return __uint_as_float(((unsigned)u) << 16);
  }
  return ((const float*)p)[i];
}
__device__ __forceinline__ unsigned short f2bf(float f) {
  unsigned u = __float_as_uint(f);
  unsigned r = (u + 0x7fffu + ((u >> 16) & 1u)) >> 16;
  return (unsigned short)r;
}
__device__ __forceinline__ unsigned pk2(float lo, float hi) {
  return (unsigned)f2bf(lo) | ((unsigned)f2bf(hi) << 16);
}
__device__ __forceinline__ int ldidx(const void* p, long long i, int i64) {
  return i64 ? (int)((const long long*)p)[i] : ((const int*)p)[i];
}
__device__ __forceinline__ float bflo(unsigned u) { return __uint_as_float(u << 16); }
__device__ __forceinline__ float bfhi(unsigned u) { return __uint_as_float(u & 0xffff0000u); }

// ---------------- merged: blocks [0,256) = edge binning; blocks [256,320) = weight prep ----------------
__global__ __launch_bounds__(256) void k_prepbin(
    const void* __restrict__ ei, const void* __restrict__ x,
    const void* __restrict__ W1_msg, const void* __restrict__ b1_msg,
    const void* __restrict__ W1_self, const void* __restrict__ b1_self,
    const void* __restrict__ gamma, const void* __restrict__ beta,
    const void* __restrict__ mean, const void* __restrict__ var,
    const void* __restrict__ W2_msg, const void* __restrict__ b2_msg,
    const void* __restrict__ W2_self, const void* __restrict__ b2_self,
    int* __restrict__ flags, unsigned short* __restrict__ PK,
    float* __restrict__ fb1s, float* __restrict__ fb2s,
    int* __restrict__ bcur, int2* __restrict__ binbuf) {
  int tid = threadIdx.x;
  int lane = tid & 63;
  if (blockIdx.x < BINBLK) {
    // ---- bin body (i64 computed locally; no dependence on flags) ----
    __shared__ int2 stage[NBK][SCAP];  // 57.3 KB
    __shared__ int scnt[NBK];
    __shared__ int gbase[NBK];
    __shared__ int s_i64;
    for (int i = tid; i < NBK; i += 256) scnt[i] = 0;
    if (tid < 64) {
      const int* p = (const int*)ei;
      int any = 0;
      for (int i = lane; i < 256; i += 64) any |= p[2 * i + 1];
      unsigned long long anyb = __ballot(any != 0);
      if (lane == 0) s_i64 = (anyb == 0ull) ? 1 : 0;
    }
    __syncthreads();
    int i64 = s_i64;
    for (long long e0 = (long long)blockIdx.x * 256; e0 < NE;
         e0 += (long long)BINBLK * 256) {
      long long e = e0 + tid;
      if (e < NE) {
        int src = ldidx(ei, e, i64);
        int dst = ldidx(ei, NE + e, i64);
        int b = dst / BNODE;
        int dl = dst - b * BNODE;
        int2 ent = make_int2(src | (dl << 16), (int)e);
        int pos = atomicAdd(&scnt[b], 1);
        if (pos < SCAP) {
          stage[b][pos] = ent;
        } else {  // rare overflow: direct global placement
          int gp = atomicAdd(&bcur[b], 1);
          binbuf[(long long)b * BCAP + gp] = ent;
        }
      }
    }
    __syncthreads();
    if (tid < NBK) {
      int cb = scnt[tid] < SCAP ? scnt[tid] : SCAP;
      gbase[tid] = atomicAdd(&bcur[tid], cb);
    }
    __syncthreads();
    // flush parallelized across the 4 waves
    int wv = tid >> 6, ln = tid & 63;
    for (int b = wv; b < NBK; b += 4) {
      int cb = scnt[b] < SCAP ? scnt[b] : SCAP;
      int gb = gbase[b];
      for (int i = ln; i < cb; i += 64)
        binbuf[(long long)b * BCAP + gb + i] = stage[b][i];
    }
  } else {
    // ---- prep body (runs concurrently with bin; first prep block publishes flags) ----
    __shared__ int s_bf;
    if (tid < 64) {
      const unsigned short* q = (const unsigned short*)x;
      int cntc = 0;
      for (int i = lane; i < 256; i += 64) {
        unsigned short w = q[2 * i];
        int e = (w >> 7) & 0xff;
        if (w == 0 || (e >= 110 && e <= 140)) cntc++;
      }
      for (int m = 1; m < 64; m <<= 1) cntc += __shfl_xor(cntc, m, 64);
      int bfv = (cntc >= 192) ? 1 : 0;
      if (blockIdx.x == BINBLK) {
        const int* p = (const int*)ei;
        int any = 0;
        for (int i = lane; i < 256; i += 64) any |= p[2 * i + 1];
        unsigned long long anyb = __ballot(any != 0);
        if (lane == 0) {
          flags[0] = (anyb == 0ull) ? 1 : 0;
          flags[1] = bfv;
        }
      }
      if (lane == 0) s_bf = bfv;
    }
    __syncthreads();
    int bf = s_bf;
    int t0 = (blockIdx.x - BINBLK) * 256 + tid;
    int stride = PREPBLK * 256;
    for (int i = t0; i < 10240; i += stride) {
      int j = i & 7, L = (i >> 3) & 63, t = (i >> 9) & 3, c = i >> 11;
      int k = c * 32 + ((L >> 4) << 3) + j;
      int col = t * 16 + (L & 15);
      float sc = ldf(gamma, col, bf) * rsqrtf(ldf(var, col, bf) + 1e-5f);
      float v;
      if (k < 64) v = ldf(W1_msg, k * 64 + col, bf) * sc;
      else if (k < 128) v = ldf(W1_self, (k - 64) * 64 + col, bf) * sc;
      else if (k < 144) v = ldf(W1_msg, (64 + k - 128) * 64 + col, bf) * sc;
      else if (k == 144) v = ldf(b1_msg, col, bf) * sc;
      else v = 0.0f;
      PK[i] = f2bf(v);
    }
    for (int i = t0; i < 2048; i += stride) {
      int j = i & 7, L = (i >> 3) & 63, t = (i >> 9) & 1, c = i >> 10;
      int k = c * 32 + ((L >> 4) << 3) + j;
      int col = t * 16 + (L & 15);
      PK[10240 + i] = f2bf(ldf(W2_msg, k * 32 + col, bf));
    }
    for (int i = t0; i < 3072; i += stride) {
      int j = i & 7, L = (i >> 3) & 63, t = (i >> 9) & 1, c = i >> 10;
      int k = c * 32 + ((L >> 4) << 3) + j;
      int col = t * 16 + (L & 15);
      float v;
      if (k < 64) v = ldf(W2_self, k * 32 + col, bf);
      else if (k < 80) v = ldf(W2_msg, k * 32 + col, bf);
      else if (k == 80) v = ldf(b2_msg, col, bf);
      else v = 0.0f;
      PK[12288 + i] = f2bf(v);
    }
    for (int i = t0; i < 64; i += stride) {
      float sc = ldf(gamma, i, bf) * rsqrtf(ldf(var, i, bf) + 1e-5f);
      fb1s[i] = ldf(b1_self, i, bf) * sc + ldf(beta, i, bf) - ldf(mean, i, bf) * sc;
    }
    for (int i = t0; i < 32; i += stride) fb2s[i] = ldf(b2_self, i, bf);
  }
}

// ---------------- phase 2: prefix + histogram + scan + row_ptr + placement ----------------
// 1024 threads: place launches only NBK=128 blocks (0.5/CU), so per-block speed is the lever.
__global__ __launch_bounds__(1024) void k_place(const int* __restrict__ bcur,
                                                const int2* __restrict__ binbuf,
                                                int* __restrict__ row_ptr,
                                                int2* __restrict__ recs) {
  __shared__ int2 outb[BCAP];  // 60 KB
  __shared__ int lh[BNODE];
  __shared__ int lexc[BNODE];
  __shared__ int lcur[BNODE];
  __shared__ int sb[NBK];
  __shared__ int s_rbase;
  int b = blockIdx.x;
  int tid = threadIdx.x;
  int base = b * BNODE;
  int nn = NN - base < BNODE ? NN - base : BNODE;
  if (tid < NBK) sb[tid] = bcur[tid];
  for (int i = tid; i < BNODE; i += 1024) lh[i] = 0;
  __syncthreads();
  // rbase = exclusive prefix of bucket totals (bcur IS the per-bucket edge count)
  if (tid < 64) {
    int v = (tid < b ? sb[tid] : 0) + (tid + 64 < b ? sb[tid + 64] : 0);
    for (int off = 32; off > 0; off >>= 1) v += __shfl_down(v, off, 64);
    if (tid == 0) s_rbase = v;
  }
  int cnt = sb[b];
  __syncthreads();
  int rbase = s_rbase;
  // pass 1: local degree histogram
  for (int i = tid; i < cnt; i += 1024) {
    int dl = (binbuf[(long long)b * BCAP + i].x >> 16) & 0x3FF;
    atomicAdd(&lh[dl], 1);
  }
  __syncthreads();
  // wave-0 exclusive scan of lh[0..nn) -> lexc (7 chunks of 64 via shfl)
  if (tid < 64) {
    int carry = 0;
    for (int c0 = 0; c0 < BNODE; c0 += 64) {
      int i = c0 + tid;
      int orig = (i < nn) ? lh[i] : 0;
      int v = orig;
      for (int off = 1; off < 64; off <<= 1) {
        int u = __shfl_up(v, off, 64);
        if (tid >= off) v += u;
      }
      if (i < nn) lexc[i] = carry + v - orig;
      carry += __shfl(v, 63, 64);
    }
  }
  __syncthreads();
  // write row_ptr for this bucket; init placement cursors
  for (int i = tid; i < nn; i += 1024) {
    int e = lexc[i];
    row_ptr[base + i] = rbase + e;
    lcur[i] = e;
  }
  if (b == NBK - 1 && tid == 0) row_ptr[NN] = rbase + cnt;
  __syncthreads();
  // pass 2: placement into LDS at final local offsets
  for (int i = tid; i < cnt; i += 1024) {
    int2 ent = binbuf[(long long)b * BCAP + i];
    int dl = (ent.x >> 16) & 0x3FF;
    int p = atomicAdd(&lcur[dl], 1);
    outb[p] = make_int2(ent.x & 0xFFFF, ent.y);
  }
  __syncthreads();
  // flush: coalesced write of sorted records
  for (int i = tid; i < cnt; i += 1024) recs[rbase + i] = outb[i];
}

// ---------------- gather 1: 8 lanes/node, unroll-4 (round-2 exact; local optimum) ----------------
// Measured floor 58 µs @ 2.85 TB/s — random-128B access-pattern roofline.
// prefetch/NT/16-lane/unroll-8/perm all regressed — do not touch.
__global__ __launch_bounds__(256) void k_gather1(
    const void* __restrict__ x, const void* __restrict__ ea,
    const int* __restrict__ row_ptr, const int2* __restrict__ recs,
    const int* __restrict__ flags, unsigned short* __restrict__ F1,
    unsigned short* __restrict__ F2) {
  int lane = threadIdx.x & 63;
  int g = lane >> 3, c = lane & 7;
  int bf = flags[1];
  long long wid = ((long long)blockIdx.x * blockDim.x + threadIdx.x) >> 6;
  long long nw = ((long long)gridDim.x * blockDim.x) >> 6;
  for (long long b = wid; b < NB; b += nw) {
    int n = (int)(b * 8 + g);
    int beg = row_ptr[n];
    int deg = row_ptr[n + 1] - beg;
    float a0 = 0.f, a1 = 0.f, a2 = 0.f, a3 = 0.f, a4 = 0.f, a5 = 0.f, a6 = 0.f, a7 = 0.f;
    float e0 = 0.f, e1 = 0.f, e2 = 0.f, e3 = 0.f;
    uint4 xw;
    if (bf) {
      const unsigned short* xs = (const unsigned short*)x;
      const unsigned short* es = (const unsigned short*)ea;
      int t = 0;
      for (; t + 4 <= deg; t += 4) {
        int2 r0 = recs[beg + t + 0];
        int2 r1 = recs[beg + t + 1];
        int2 r2 = recs[beg + t + 2];
        int2 r3 = recs[beg + t + 3];
        uint4 w0 = *((const uint4*)(xs + ((long long)r0.x << 6)) + c);
        uint4 w1 = *((const uint4*)(xs + ((long long)r1.x << 6)) + c);
        uint4 w2 = *((const uint4*)(xs + ((long long)r2.x << 6)) + c);
        uint4 w3 = *((const uint4*)(xs + ((long long)r3.x << 6)) + c);
        a0 += bflo(w0.x) + bflo(w1.x) + bflo(w2.x) + bflo(w3.x);
        a1 += bfhi(w0.x) + bfhi(w1.x) + bfhi(w2.x) + bfhi(w3.x);
        a2 += bflo(w0.y) + bflo(w1.y) + bflo(w2.y) + bflo(w3.y);
        a3 += bfhi(w0.y) + bfhi(w1.y) + bfhi(w2.y) + bfhi(w3.y);
        a4 += bflo(w0.z) + bflo(w1.z) + bflo(w2.z) + bflo(w3.z);
        a5 += bfhi(w0.z) + bfhi(w1.z) + bfhi(w2.z) + bfhi(w3.z);
        a6 += bflo(w0.w) + bflo(w1.w) + bflo(w2.w) + bflo(w3.w);
        a7 += bfhi(w0.w) + bfhi(w1.w) + bfhi(w2.w) + bfhi(w3.w);
        if (c < 4) {
          uint2 q0 = *((const uint2*)(es + ((long long)r0.y << 4)) + c);
          uint2 q1 = *((const uint2*)(es + ((long long)r1.y << 4)) + c);
          uint2 q2 = *((const uint2*)(es + ((long long)r2.y << 4)) + c);
          uint2 q3 = *((const uint2*)(es + ((long long)r3.y << 4)) + c);
          e0 += bflo(q0.x) + bflo(q1.x) + bflo(q2.x) + bflo(q3.x);
          e1 += bfhi(q0.x) + bfhi(q1.x) + bfhi(q2.x) + bfhi(q3.x);
          e2 += bflo(q0.y) + bflo(q1.y) + bflo(q2.y) + bflo(q3.y);
          e3 += bfhi(q0.y) + bfhi(q1.y) + bfhi(q2.y) + bfhi(q3.y);
        }
      }
      for (; t < deg; ++t) {
        int2 r = recs[beg + t];
        uint4 w = *((const uint4*)(xs + ((long long)r.x << 6)) + c);
        a0 += bflo(w.x); a1 += bfhi(w.x);
        a2 += bflo(w.y); a3 += bfhi(w.y);
        a4 += bflo(w.z); a5 += bfhi(w.z);
        a6 += bflo(w.w); a7 += bfhi(w.w);
        if (c < 4) {
          uint2 q = *((const uint2*)(es + ((long long)r.y << 4)) + c);
          e0 += bflo(q.x); e1 += bfhi(q.x);
          e2 += bflo(q.y); e3 += bfhi(q.y);
        }
      }
      xw = *((const uint4*)(xs + ((long long)n << 6)) + c);
    } else {
      const float* xf = (const float*)x;
      const float* ef = (const float*)ea;
      for (int t = 0; t < deg; ++t) {
        int2 r = recs[beg + t];
        float4 w0 = *((const float4*)(xf + ((long long)r.x << 6)) + c * 2);
        float4 w1 = *((const float4*)(xf + ((long long)r.x << 6)) + c * 2 + 1);
        a0 += w0.x; a1 += w0.y; a2 += w0.z; a3 += w0.w;
        a4 += w1.x; a5 += w1.y; a6 += w1.z; a7 += w1.w;
        if (c < 4) {
          float4 q = *((const float4*)(ef + ((long long)r.y << 4)) + c);
          e0 += q.x; e1 += q.y; e2 += q.z; e3 += q.w;
        }
      }
      float4 p0 = *((const float4*)(xf + ((long long)n << 6)) + c * 2);
      float4 p1 = *((const float4*)(xf + ((long long)n << 6)) + c * 2 + 1);
      xw = make_uint4(pk2(p0.x, p0.y), pk2(p0.z, p0.w), pk2(p1.x, p1.y), pk2(p1.z, p1.w));
    }
    unsigned short* f1 = F1 + (long long)n * 160;
    unsigned short* f2 = F2 + (long long)n * 96;
    *((uint4*)f1 + c) = make_uint4(pk2(a0, a1), pk2(a2, a3), pk2(a4, a5), pk2(a6, a7));
    *((uint4*)(f1 + 64) + c) = xw;
    if (c < 4) {
      uint2 sp = make_uint2(pk2(e0, e1), pk2(e2, e3));
      *((uint2*)(f1 + 128) + c) = sp;
      *((uint2*)(f2 + 64) + c) = sp;
    }
    if (c == 4) {
      unsigned d = (unsigned)f2bf((float)deg);
      *((uint4*)(f1 + 144)) = make_uint4(d, 0u, 0u, 0u);
      *((uint4*)(f2 + 80)) = make_uint4(d, 0u, 0u, 0u);
    }
    if (c == 5) {
      *((uint4*)(f1 + 152)) = make_uint4(0u, 0u, 0u, 0u);
      *((uint4*)(f2 + 88)) = make_uint4(0u, 0u, 0u, 0u);
    }
  }
}

// ---------------- gemm 1 (MFMA): F1@B1 + bias -> ReLU -> F2[0..64) ; fused Y2 = h@BY ----------------
__global__ __launch_bounds__(256) void k_gemm1(
    const unsigned short* __restrict__ F1, const unsigned short* __restrict__ PK,
    const float* __restrict__ fb1s, unsigned short* __restrict__ F2,
    unsigned short* __restrict__ Y2B) {
  // per-wave LDS staging for the h-tile transpose (stride 72 shorts = conflict-light)
  __shared__ unsigned short hsh[4][16 * 72];
  int lane = threadIdx.x & 63;
  int wv = threadIdx.x >> 6;
  int m = lane & 15, quad = lane >> 4;
  unsigned short* hs = hsh[wv];
  short8x Bf[20];
#pragma unroll
  for (int s = 0; s < 20; ++s) Bf[s] = *(const short8x*)(PK + (s * 64 + lane) * 8);
  short8x By[4];
#pragma unroll
  for (int s = 0; s < 4; ++s) By[s] = *(const short8x*)(PK + 10240 + (s * 64 + lane) * 8);
  long long gw = (long long)blockIdx.x * 4 + wv;
  long long nw = (long long)gridDim.x * 4;
  for (long long tile = gw; tile < NT; tile += nw) {
    long long n0 = tile * 16;
    const unsigned short* f1 = F1 + (n0 + m) * 160 + quad * 8;
    short8x A[5];
#pragma unroll
    for (int cc = 0; cc < 5; ++cc) A[cc] = *(const short8x*)(f1 + cc * 32);
    f32x4 acc[4];
#pragma unroll
    for (int t = 0; t < 4; ++t) {
      float b = fb1s[t * 16 + m];
      acc[t] = (f32x4){b, b, b, b};
    }
#pragma unroll
    for (int cc = 0; cc < 5; ++cc) {
#pragma unroll
      for (int t = 0; t < 4; ++t)
        acc[t] = __builtin_amdgcn_mfma_f32_16x16x32_bf16(A[cc], Bf[cc * 4 + t], acc[t], 0, 0, 0);
    }
    // write h to F2 (plain, stays in L2 for gg2) and stage bf16-rounded h in LDS
#pragma unroll
    for (int t = 0; t < 4; ++t) {
#pragma unroll
      for (int i = 0; i < 4; ++i) {
        float h = fmaxf(acc[t][i], 0.0f);
        unsigned short us = f2bf(h);
        F2[(n0 + quad * 4 + i) * 96 + t * 16 + m] = us;
        hs[(quad * 4 + i) * 72 + t * 16 + m] = us;
      }
    }
    __builtin_amdgcn_sched_barrier(0);  // keep ds_reads after ds_writes (wave-synchronous)
    f32x4 yacc[2];
    yacc[0] = (f32x4){0.f, 0.f, 0.f, 0.f};
    yacc[1] = (f32x4){0.f, 0.f, 0.f, 0.f};
#pragma unroll
    for (int cc = 0; cc < 2; ++cc) {
      short8x Ah = *(const short8x*)(hs + m * 72 + cc * 32 + quad * 8);
#pragma unroll
      for (int t = 0; t < 2; ++t)
        yacc[t] = __builtin_amdgcn_mfma_f32_16x16x32_bf16(Ah, By[cc * 2 + t], yacc[t], 0, 0, 0);
    }
#pragma unroll
    for (int t = 0; t < 2; ++t) {
#pragma unroll
      for (int i = 0; i < 4; ++i)
        Y2B[(n0 + quad * 4 + i) * 32 + t * 16 + m] = f2bf(yacc[t][i]);
    }
    __builtin_amdgcn_sched_barrier(0);
  }
}

// ---------------- fused gather2 + gemm2: per 16-node tile, 2 waves cooperate ----------------
// wave-half th gathers rows th*8..th*8+7 (8 lanes/node, unroll-4 — the proven loop),
// stages f32 sums in LDS, barrier, then does the MFMA for its t=th column half.
// 1563 blocks x 4 waves = 6252 waves — same gather TLP as standalone gather2.
__global__ __launch_bounds__(256) void k_gg2(
    const unsigned short* __restrict__ F2, const unsigned short* __restrict__ PK,
    const float* __restrict__ fb2s, const unsigned short* __restrict__ Y2B,
    const int* __restrict__ row_ptr, const int2* __restrict__ recs,
    const int* __restrict__ flags, void* __restrict__ out) {
  __shared__ float sums[2][16][33];  // [tile-pair][row][32ch padded] = 4.2 KB
  int tid = threadIdx.x;
  int lane = tid & 63;
  int wv = tid >> 6;
  int tp = wv >> 1;   // which tile of the block's pair
  int th = wv & 1;    // row-half for gather; t-half for MFMA
  long long tile = (long long)blockIdx.x * 2 + tp;
  int valid = tile < NT;
  if (valid) {
    int g = lane >> 3, c = lane & 7;
    int n = (int)(tile * 16 + th * 8 + g);
    int beg = row_ptr[n];
    int deg = row_ptr[n + 1] - beg;
    float s0 = 0.f, s1 = 0.f, s2 = 0.f, s3 = 0.f;
    int t = 0;
    for (; t + 4 <= deg; t += 4) {
      int2 r0 = recs[beg + t + 0];
      int2 r1 = recs[beg + t + 1];
      int2 r2 = recs[beg + t + 2];
      int2 r3 = recs[beg + t + 3];
      uint2 q0 = *((const uint2*)(Y2B + (long long)r0.x * 32) + c);
      uint2 q1 = *((const uint2*)(Y2B + (long long)r1.x * 32) + c);
      uint2 q2 = *((const uint2*)(Y2B + (long long)r2.x * 32) + c);
      uint2 q3 = *((const uint2*)(Y2B + (long long)r3.x * 32) + c);
      s0 += bflo(q0.x) + bflo(q1.x) + bflo(q2.x) + bflo(q3.x);
      s1 += bfhi(q0.x) + bfhi(q1.x) + bfhi(q2.x) + bfhi(q3.x);
      s2 += bflo(q0.y) + bflo(q1.y) + bflo(q2.y) + bflo(q3.y);
      s3 += bfhi(q0.y) + bfhi(q1.y) + bfhi(q2.y) + bfhi(q3.y);
    }
    for (; t < deg; ++t) {
      int2 r = recs[beg + t];
      uint2 q = *((const uint2*)(Y2B + (long long)r.x * 32) + c);
      s0 += bflo(q.x); s1 += bfhi(q.x);
      s2 += bflo(q.y); s3 += bfhi(q.y);
    }
    float* sr = &sums[tp][th * 8 + g][c * 4];
    sr[0] = s0; sr[1] = s1; sr[2] = s2; sr[3] = s3;
  }
  __syncthreads();
  if (valid) {
    int m = lane & 15, quad = lane >> 4;
    int bf = flags[1];
    long long n0 = tile * 16;
    const unsigned short* f2 = F2 + (n0 + m) * 96 + quad * 8;
    short8x A[3];
#pragma unroll
    for (int cc = 0; cc < 3; ++cc) A[cc] = *(const short8x*)(f2 + cc * 32);
    short8x Bf[3];
#pragma unroll
    for (int cc = 0; cc < 3; ++cc)
      Bf[cc] = *(const short8x*)(PK + 12288 + ((cc * 2 + th) * 64 + lane) * 8);
    f32x4 acc;
    float fb = fb2s[th * 16 + m];
#pragma unroll
    for (int i = 0; i < 4; ++i) acc[i] = fb + sums[tp][quad * 4 + i][th * 16 + m];
#pragma unroll
    for (int cc = 0; cc < 3; ++cc)
      acc = __builtin_amdgcn_mfma_f32_16x16x32_bf16(A[cc], Bf[cc], acc, 0, 0, 0);
#pragma unroll
    for (int i = 0; i < 4; ++i) {
      long long idx = (n0 + quad * 4 + i) * 32 + th * 16 + m;
      if (bf) ((unsigned short*)out)[idx] = f2bf(acc[i]);
      else ((float*)out)[idx] = acc[i];
    }
  }
}

extern "C" void kernel_launch(void* const* d_in, const int* in_sizes, int n_in,
                              void* d_out, int out_size, void* d_ws, size_t ws_size,
                              hipStream_t stream) {
  const void* x = d_in[0];
  const void* ei = d_in[1];
  const void* ea = d_in[2];
  const void* W1_msg = d_in[3];
  const void* b1_msg = d_in[4];
  const void* W1_self = d_in[5];
  const void* b1_self = d_in[6];
  const void* gamma = d_in[7];
  const void* beta = d_in[8];
  const void* mean = d_in[9];
  const void* var = d_in[10];
  const void* W2_msg = d_in[11];
  const void* b2_msg = d_in[12];
  const void* W2_self = d_in[13];
  const void* b2_self = d_in[14];

  float* ws = (float*)d_ws;
  int* row_ptr = (int*)(ws + OFF_ROW);
  int2* recs = (int2*)(ws + OFF_RECS);
  int* flags = (int*)(ws + OFF_FLAGS);
  unsigned short* PK = (unsigned short*)(ws + OFF_PK);
  float* fb1s = ws + OFF_FB1S;
  float* fb2s = ws + OFF_FB2S;
  unsigned short* F1 = (unsigned short*)(ws + OFF_F1);
  int2* binbuf = (int2*)(ws + OFF_F1);  // aliases F1 (dead before gather1)
  unsigned short* F2 = (unsigned short*)(ws + OFF_F2);
  unsigned short* Y2B = (unsigned short*)(ws + OFF_Y2B);
  int* bcur = (int*)(ws + OFF_BCUR);

  hipMemsetAsync(bcur, 0, NBK * sizeof(int), stream);
  hipLaunchKernelGGL(k_prepbin, dim3(BINBLK + PREPBLK), dim3(256), 0, stream, ei, x,
                     W1_msg, b1_msg, W1_self, b1_self, gamma, beta, mean, var, W2_msg,
                     b2_msg, W2_self, b2_self, flags, PK, fb1s, fb2s, bcur, binbuf);
  hipLaunchKernelGGL(k_place, dim3(NBK), dim3(1024), 0, stream, bcur, binbuf, row_ptr,
                     recs);

  int gblocks = (NB + 3) / 4;
  hipLaunchKernelGGL(k_gather1, dim3(gblocks), dim3(256), 0, stream, x, ea, row_ptr,
                     recs, flags, F1, F2);
  int mblocks = (NT + 3) / 4;
  hipLaunchKernelGGL(k_gemm1, dim3(mblocks), dim3(256), 0, stream, F1, PK, fb1s, F2,
                     Y2B);
  hipLaunchKernelGGL(k_gg2, dim3((NT + 1) / 2), dim3(256), 0, stream, F2, PK, fb2s,
                     Y2B, row_ptr, recs, flags, d_out);
}

// Round 10
// 206.975 us; speedup vs baseline: 1.2874x; 1.0258x over previous
//
#include <hip/hip_runtime.h>

#define NN 50000
#define NE 800000
#define NT 3125        // NN/16 mfma tiles
#define NBK 128        // coarse buckets
#define BNODE 391      // nodes per bucket (391*128 = 50048 >= NN)
#define BCAP 7680      // bucket capacity (mean 6250, +18 sigma)
#define SCAP 56        // per-block LDS stage capacity per bucket
#define BINBLK 256     // bin-part blocks in k_prepbin
#define PREPBLK 64     // prep-part blocks in k_prepbin

typedef __attribute__((ext_vector_type(8))) short short8x;
typedef __attribute__((ext_vector_type(4))) float f32x4;

// ws layout (float-index offsets)
#define OFF_ROW   ((long long)NN)     // NN+1 ints (row_ptr)
#define OFF_RECS  (3LL*NN + 16)       // NE int2
#define OFF_FLAGS (35LL*NN + 16)      // ints
#define OFF_PK    (35LL*NN + 256)     // 15360 ushorts (16B-aligned)
#define OFF_FB1S  (35LL*NN + 7936)    // 64 f32
#define OFF_FB2S  (35LL*NN + 8000)    // 32 f32
#define OFF_F1    (36LL*NN)           // (binbuf lives here; F1 buffer eliminated)
#define OFF_F2    (116LL*NN)          // NN*96 bf16
#define OFF_Y2B   (164LL*NN)          // NN*32 bf16
#define OFF_BCUR  (212LL*NN)          // 128 ints

__device__ __forceinline__ float ldf(const void* p, long long i, int bf16) {
  if (bf16) {
    unsigned short u = ((const unsigned short*)p)[i];
    return __uint_as_float(((unsigned)u) << 16);
  }
  return ((const float*)p)[i];
}
__device__ __forceinline__ unsigned short f2bf(float f) {
  unsigned u = __float_as_uint(f);
  unsigned r = (u + 0x7fffu + ((u >> 16) & 1u)) >> 16;
  return (unsigned short)r;
}
__device__ __forceinline__ unsigned pk2(float lo, float hi) {
  return (unsigned)f2bf(lo) | ((unsigned)f2bf(hi) << 16);
}
__device__ __forceinline__ int ldidx(const void* p, long long i, int i64) {
  return i64 ? (int)((const long long*)p)[i] : ((const int*)p)[i];
}
__device__ __forceinline__ float bflo(unsigned u) { return __uint_as_float(u << 16); }
__device__ __forceinline__ float bfhi(unsigned u) { return __uint_as_float(u & 0xffff0000u); }

// ---------------- merged: blocks [0,256) = edge binning; blocks [256,320) = weight prep ----------------
__global__ __launch_bounds__(256) void k_prepbin(
    const void* __restrict__ ei, const void* __restrict__ x,
    const void* __restrict__ W1_msg, const void* __restrict__ b1_msg,
    const void* __restrict__ W1_self, const void* __restrict__ b1_self,
    const void* __restrict__ gamma, const void* __restrict__ beta,
    const void* __restrict__ mean, const void* __restrict__ var,
    const void* __restrict__ W2_msg, const void* __restrict__ b2_msg,
    const void* __restrict__ W2_self, const void* __restrict__ b2_self,
    int* __restrict__ flags, unsigned short* __restrict__ PK,
    float* __restrict__ fb1s, float* __restrict__ fb2s,
    int* __restrict__ bcur, int2* __restrict__ binbuf) {
  int tid = threadIdx.x;
  int lane = tid & 63;
  if (blockIdx.x < BINBLK) {
    // ---- bin body (i64 computed locally; no dependence on flags) ----
    __shared__ int2 stage[NBK][SCAP];  // 57.3 KB
    __shared__ int scnt[NBK];
    __shared__ int gbase[NBK];
    __shared__ int s_i64;
    for (int i = tid; i < NBK; i += 256) scnt[i] = 0;
    if (tid < 64) {
      const int* p = (const int*)ei;
      int any = 0;
      for (int i = lane; i < 256; i += 64) any |= p[2 * i + 1];
      unsigned long long anyb = __ballot(any != 0);
      if (lane == 0) s_i64 = (anyb == 0ull) ? 1 : 0;
    }
    __syncthreads();
    int i64 = s_i64;
    for (long long e0 = (long long)blockIdx.x * 256; e0 < NE;
         e0 += (long long)BINBLK * 256) {
      long long e = e0 + tid;
      if (e < NE) {
        int src = ldidx(ei, e, i64);
        int dst = ldidx(ei, NE + e, i64);
        int b = dst / BNODE;
        int dl = dst - b * BNODE;
        int2 ent = make_int2(src | (dl << 16), (int)e);
        int pos = atomicAdd(&scnt[b], 1);
        if (pos < SCAP) {
          stage[b][pos] = ent;
        } else {  // rare overflow: direct global placement
          int gp = atomicAdd(&bcur[b], 1);
          binbuf[(long long)b * BCAP + gp] = ent;
        }
      }
    }
    __syncthreads();
    if (tid < NBK) {
      int cb = scnt[tid] < SCAP ? scnt[tid] : SCAP;
      gbase[tid] = atomicAdd(&bcur[tid], cb);
    }
    __syncthreads();
    // flush parallelized across the 4 waves
    int wv = tid >> 6, ln = tid & 63;
    for (int b = wv; b < NBK; b += 4) {
      int cb = scnt[b] < SCAP ? scnt[b] : SCAP;
      int gb = gbase[b];
      for (int i = ln; i < cb; i += 64)
        binbuf[(long long)b * BCAP + gb + i] = stage[b][i];
    }
  } else {
    // ---- prep body (runs concurrently with bin; first prep block publishes flags) ----
    __shared__ int s_bf;
    if (tid < 64) {
      const unsigned short* q = (const unsigned short*)x;
      int cntc = 0;
      for (int i = lane; i < 256; i += 64) {
        unsigned short w = q[2 * i];
        int e = (w >> 7) & 0xff;
        if (w == 0 || (e >= 110 && e <= 140)) cntc++;
      }
      for (int m = 1; m < 64; m <<= 1) cntc += __shfl_xor(cntc, m, 64);
      int bfv = (cntc >= 192) ? 1 : 0;
      if (blockIdx.x == BINBLK) {
        const int* p = (const int*)ei;
        int any = 0;
        for (int i = lane; i < 256; i += 64) any |= p[2 * i + 1];
        unsigned long long anyb = __ballot(any != 0);
        if (lane == 0) {
          flags[0] = (anyb == 0ull) ? 1 : 0;
          flags[1] = bfv;
        }
      }
      if (lane == 0) s_bf = bfv;
    }
    __syncthreads();
    int bf = s_bf;
    int t0 = (blockIdx.x - BINBLK) * 256 + tid;
    int stride = PREPBLK * 256;
    for (int i = t0; i < 10240; i += stride) {
      int j = i & 7, L = (i >> 3) & 63, t = (i >> 9) & 3, c = i >> 11;
      int k = c * 32 + ((L >> 4) << 3) + j;
      int col = t * 16 + (L & 15);
      float sc = ldf(gamma, col, bf) * rsqrtf(ldf(var, col, bf) + 1e-5f);
      float v;
      if (k < 64) v = ldf(W1_msg, k * 64 + col, bf) * sc;
      else if (k < 128) v = ldf(W1_self, (k - 64) * 64 + col, bf) * sc;
      else if (k < 144) v = ldf(W1_msg, (64 + k - 128) * 64 + col, bf) * sc;
      else if (k == 144) v = ldf(b1_msg, col, bf) * sc;
      else v = 0.0f;
      PK[i] = f2bf(v);
    }
    for (int i = t0; i < 2048; i += stride) {
      int j = i & 7, L = (i >> 3) & 63, t = (i >> 9) & 1, c = i >> 10;
      int k = c * 32 + ((L >> 4) << 3) + j;
      int col = t * 16 + (L & 15);
      PK[10240 + i] = f2bf(ldf(W2_msg, k * 32 + col, bf));
    }
    for (int i = t0; i < 3072; i += stride) {
      int j = i & 7, L = (i >> 3) & 63, t = (i >> 9) & 1, c = i >> 10;
      int k = c * 32 + ((L >> 4) << 3) + j;
      int col = t * 16 + (L & 15);
      float v;
      if (k < 64) v = ldf(W2_self, k * 32 + col, bf);
      else if (k < 80) v = ldf(W2_msg, k * 32 + col, bf);
      else if (k == 80) v = ldf(b2_msg, col, bf);
      else v = 0.0f;
      PK[12288 + i] = f2bf(v);
    }
    for (int i = t0; i < 64; i += stride) {
      float sc = ldf(gamma, i, bf) * rsqrtf(ldf(var, i, bf) + 1e-5f);
      fb1s[i] = ldf(b1_self, i, bf) * sc + ldf(beta, i, bf) - ldf(mean, i, bf) * sc;
    }
    for (int i = t0; i < 32; i += stride) fb2s[i] = ldf(b2_self, i, bf);
  }
}

// ---------------- phase 2: prefix + histogram + scan + row_ptr + placement ----------------
__global__ __launch_bounds__(1024) void k_place(const int* __restrict__ bcur,
                                                const int2* __restrict__ binbuf,
                                                int* __restrict__ row_ptr,
                                                int2* __restrict__ recs) {
  __shared__ int2 outb[BCAP];  // 60 KB
  __shared__ int lh[BNODE];
  __shared__ int lexc[BNODE];
  __shared__ int lcur[BNODE];
  __shared__ int sb[NBK];
  __shared__ int s_rbase;
  int b = blockIdx.x;
  int tid = threadIdx.x;
  int base = b * BNODE;
  int nn = NN - base < BNODE ? NN - base : BNODE;
  if (tid < NBK) sb[tid] = bcur[tid];
  for (int i = tid; i < BNODE; i += 1024) lh[i] = 0;
  __syncthreads();
  if (tid < 64) {
    int v = (tid < b ? sb[tid] : 0) + (tid + 64 < b ? sb[tid + 64] : 0);
    for (int off = 32; off > 0; off >>= 1) v += __shfl_down(v, off, 64);
    if (tid == 0) s_rbase = v;
  }
  int cnt = sb[b];
  __syncthreads();
  int rbase = s_rbase;
  for (int i = tid; i < cnt; i += 1024) {
    int dl = (binbuf[(long long)b * BCAP + i].x >> 16) & 0x3FF;
    atomicAdd(&lh[dl], 1);
  }
  __syncthreads();
  if (tid < 64) {
    int carry = 0;
    for (int c0 = 0; c0 < BNODE; c0 += 64) {
      int i = c0 + tid;
      int orig = (i < nn) ? lh[i] : 0;
      int v = orig;
      for (int off = 1; off < 64; off <<= 1) {
        int u = __shfl_up(v, off, 64);
        if (tid >= off) v += u;
      }
      if (i < nn) lexc[i] = carry + v - orig;
      carry += __shfl(v, 63, 64);
    }
  }
  __syncthreads();
  for (int i = tid; i < nn; i += 1024) {
    int e = lexc[i];
    row_ptr[base + i] = rbase + e;
    lcur[i] = e;
  }
  if (b == NBK - 1 && tid == 0) row_ptr[NN] = rbase + cnt;
  __syncthreads();
  for (int i = tid; i < cnt; i += 1024) {
    int2 ent = binbuf[(long long)b * BCAP + i];
    int dl = (ent.x >> 16) & 0x3FF;
    int p = atomicAdd(&lcur[dl], 1);
    outb[p] = make_int2(ent.x & 0xFFFF, ent.y);
  }
  __syncthreads();
  for (int i = tid; i < cnt; i += 1024) recs[rbase + i] = outb[i];
}

// ---------------- fused gather1 + gemm1: 2 waves/tile; gather -> LDS F1-row -> MFMA ----------------
// Gather loop is the proven round-2 body (58 µs floor — do not touch). F1 global buffer
// eliminated (16 MB write + 16 MB read). 1563 blocks x 4 waves = 6252 waves = same TLP.
__global__ __launch_bounds__(256) void k_gg1(
    const void* __restrict__ x, const void* __restrict__ ea,
    const int* __restrict__ row_ptr, const int2* __restrict__ recs,
    const int* __restrict__ flags, const unsigned short* __restrict__ PK,
    const float* __restrict__ fb1s, unsigned short* __restrict__ F2,
    unsigned short* __restrict__ Y2B) {
  __shared__ __align__(16) unsigned short fs[2][16][168];  // F1-rows, stride 336B = 21x16B (conflict-light)
  __shared__ __align__(16) unsigned short hsh[2][16 * 72]; // h transpose staging
  int tid = threadIdx.x;
  int lane = tid & 63;
  int wv = tid >> 6;
  int tp = wv >> 1, th = wv & 1;
  long long tile = (long long)blockIdx.x * 2 + tp;
  int valid = tile < NT;
  int bf = flags[1];
  int m = lane & 15, quad = lane >> 4;
  if (valid) {
    int g = lane >> 3, c = lane & 7;
    int n = (int)(tile * 16 + th * 8 + g);
    int beg = row_ptr[n];
    int deg = row_ptr[n + 1] - beg;
    float a0 = 0.f, a1 = 0.f, a2 = 0.f, a3 = 0.f, a4 = 0.f, a5 = 0.f, a6 = 0.f, a7 = 0.f;
    float e0 = 0.f, e1 = 0.f, e2 = 0.f, e3 = 0.f;
    uint4 xw;
    if (bf) {
      const unsigned short* xs = (const unsigned short*)x;
      const unsigned short* es = (const unsigned short*)ea;
      int t = 0;
      for (; t + 4 <= deg; t += 4) {
        int2 r0 = recs[beg + t + 0];
        int2 r1 = recs[beg + t + 1];
        int2 r2 = recs[beg + t + 2];
        int2 r3 = recs[beg + t + 3];
        uint4 w0 = *((const uint4*)(xs + ((long long)r0.x << 6)) + c);
        uint4 w1 = *((const uint4*)(xs + ((long long)r1.x << 6)) + c);
        uint4 w2 = *((const uint4*)(xs + ((long long)r2.x << 6)) + c);
        uint4 w3 = *((const uint4*)(xs + ((long long)r3.x << 6)) + c);
        a0 += bflo(w0.x) + bflo(w1.x) + bflo(w2.x) + bflo(w3.x);
        a1 += bfhi(w0.x) + bfhi(w1.x) + bfhi(w2.x) + bfhi(w3.x);
        a2 += bflo(w0.y) + bflo(w1.y) + bflo(w2.y) + bflo(w3.y);
        a3 += bfhi(w0.y) + bfhi(w1.y) + bfhi(w2.y) + bfhi(w3.y);
        a4 += bflo(w0.z) + bflo(w1.z) + bflo(w2.z) + bflo(w3.z);
        a5 += bfhi(w0.z) + bfhi(w1.z) + bfhi(w2.z) + bfhi(w3.z);
        a6 += bflo(w0.w) + bflo(w1.w) + bflo(w2.w) + bflo(w3.w);
        a7 += bfhi(w0.w) + bfhi(w1.w) + bfhi(w2.w) + bfhi(w3.w);
        if (c < 4) {
          uint2 q0 = *((const uint2*)(es + ((long long)r0.y << 4)) + c);
          uint2 q1 = *((const uint2*)(es + ((long long)r1.y << 4)) + c);
          uint2 q2 = *((const uint2*)(es + ((long long)r2.y << 4)) + c);
          uint2 q3 = *((const uint2*)(es + ((long long)r3.y << 4)) + c);
          e0 += bflo(q0.x) + bflo(q1.x) + bflo(q2.x) + bflo(q3.x);
          e1 += bfhi(q0.x) + bfhi(q1.x) + bfhi(q2.x) + bfhi(q3.x);
          e2 += bflo(q0.y) + bflo(q1.y) + bflo(q2.y) + bflo(q3.y);
          e3 += bfhi(q0.y) + bfhi(q1.y) + bfhi(q2.y) + bfhi(q3.y);
        }
      }
      for (; t < deg; ++t) {
        int2 r = recs[beg + t];
        uint4 w = *((const uint4*)(xs + ((long long)r.x << 6)) + c);
        a0 += bflo(w.x); a1 += bfhi(w.x);
        a2 += bflo(w.y); a3 += bfhi(w.y);
        a4 += bflo(w.z); a5 += bfhi(w.z);
        a6 += bflo(w.w); a7 += bfhi(w.w);
        if (c < 4) {
          uint2 q = *((const uint2*)(es + ((long long)r.y << 4)) + c);
          e0 += bflo(q.x); e1 += bfhi(q.x);
          e2 += bflo(q.y); e3 += bfhi(q.y);
        }
      }
      xw = *((const uint4*)(xs + ((long long)n << 6)) + c);
    } else {
      const float* xf = (const float*)x;
      const float* ef = (const float*)ea;
      for (int t = 0; t < deg; ++t) {
        int2 r = recs[beg + t];
        float4 w0 = *((const float4*)(xf + ((long long)r.x << 6)) + c * 2);
        float4 w1 = *((const float4*)(xf + ((long long)r.x << 6)) + c * 2 + 1);
        a0 += w0.x; a1 += w0.y; a2 += w0.z; a3 += w0.w;
        a4 += w1.x; a5 += w1.y; a6 += w1.z; a7 += w1.w;
        if (c < 4) {
          float4 q = *((const float4*)(ef + ((long long)r.y << 4)) + c);
          e0 += q.x; e1 += q.y; e2 += q.z; e3 += q.w;
        }
      }
      float4 p0 = *((const float4*)(xf + ((long long)n << 6)) + c * 2);
      float4 p1 = *((const float4*)(xf + ((long long)n << 6)) + c * 2 + 1);
      xw = make_uint4(pk2(p0.x, p0.y), pk2(p0.z, p0.w), pk2(p1.x, p1.y), pk2(p1.z, p1.w));
    }
    unsigned short* f1 = &fs[tp][th * 8 + g][0];
    unsigned short* f2 = F2 + (long long)n * 96;
    *((uint4*)f1 + c) = make_uint4(pk2(a0, a1), pk2(a2, a3), pk2(a4, a5), pk2(a6, a7));
    *((uint4*)(f1 + 64) + c) = xw;
    if (c < 4) {
      uint2 sp = make_uint2(pk2(e0, e1), pk2(e2, e3));
      *((uint2*)(f1 + 128) + c) = sp;
      *((uint2*)(f2 + 64) + c) = sp;
    }
    if (c == 4) {
      unsigned d = (unsigned)f2bf((float)deg);
      *((uint4*)(f1 + 144)) = make_uint4(d, 0u, 0u, 0u);
      *((uint4*)(f2 + 80)) = make_uint4(d, 0u, 0u, 0u);
    }
    if (c == 5) {
      *((uint4*)(f1 + 152)) = make_uint4(0u, 0u, 0u, 0u);
      *((uint4*)(f2 + 88)) = make_uint4(0u, 0u, 0u, 0u);
    }
  }
  __syncthreads();
  if (valid) {
    long long n0 = tile * 16;
    const unsigned short* f1 = &fs[tp][m][quad * 8];
    short8x A[5];
#pragma unroll
    for (int cc = 0; cc < 5; ++cc) A[cc] = *(const short8x*)(f1 + cc * 32);
    short8x Bf[10];
#pragma unroll
    for (int cc = 0; cc < 5; ++cc)
#pragma unroll
      for (int j = 0; j < 2; ++j)
        Bf[cc * 2 + j] = *(const short8x*)(PK + ((cc * 4 + th * 2 + j) * 64 + lane) * 8);
    f32x4 acc[2];
#pragma unroll
    for (int j = 0; j < 2; ++j) {
      float b = fb1s[(th * 2 + j) * 16 + m];
      acc[j] = (f32x4){b, b, b, b};
    }
#pragma unroll
    for (int cc = 0; cc < 5; ++cc)
#pragma unroll
      for (int j = 0; j < 2; ++j)
        acc[j] = __builtin_amdgcn_mfma_f32_16x16x32_bf16(A[cc], Bf[cc * 2 + j], acc[j], 0, 0, 0);
    // write h to F2 (plain, stays in L2 for gg2) and stage into shared hsh for Y-gemm
    unsigned short* hs = hsh[tp];
#pragma unroll
    for (int j = 0; j < 2; ++j) {
#pragma unroll
      for (int i = 0; i < 4; ++i) {
        float h = fmaxf(acc[j][i], 0.0f);
        unsigned short us = f2bf(h);
        F2[(n0 + quad * 4 + i) * 96 + (th * 2 + j) * 16 + m] = us;
        hs[(quad * 4 + i) * 72 + (th * 2 + j) * 16 + m] = us;
      }
    }
  }
  __syncthreads();
  if (valid) {
    long long n0 = tile * 16;
    const unsigned short* hs = hsh[tp];
    f32x4 yacc = (f32x4){0.f, 0.f, 0.f, 0.f};
#pragma unroll
    for (int cc = 0; cc < 2; ++cc) {
      short8x Ah = *(const short8x*)(hs + m * 72 + cc * 32 + quad * 8);
      short8x By = *(const short8x*)(PK + 10240 + ((cc * 2 + th) * 64 + lane) * 8);
      yacc = __builtin_amdgcn_mfma_f32_16x16x32_bf16(Ah, By, yacc, 0, 0, 0);
    }
#pragma unroll
    for (int i = 0; i < 4; ++i)
      Y2B[(n0 + quad * 4 + i) * 32 + th * 16 + m] = f2bf(yacc[i]);
  }
}

// ---------------- fused gather2 + gemm2 (round-9 proven form) ----------------
__global__ __launch_bounds__(256) void k_gg2(
    const unsigned short* __restrict__ F2, const unsigned short* __restrict__ PK,
    const float* __restrict__ fb2s, const unsigned short* __restrict__ Y2B,
    const int* __restrict__ row_ptr, const int2* __restrict__ recs,
    const int* __restrict__ flags, void* __restrict__ out) {
  __shared__ float sums[2][16][33];  // [tile-pair][row][32ch padded]
  int tid = threadIdx.x;
  int lane = tid & 63;
  int wv = tid >> 6;
  int tp = wv >> 1;
  int th = wv & 1;
  long long tile = (long long)blockIdx.x * 2 + tp;
  int valid = tile < NT;
  if (valid) {
    int g = lane >> 3, c = lane & 7;
    int n = (int)(tile * 16 + th * 8 + g);
    int beg = row_ptr[n];
    int deg = row_ptr[n + 1] - beg;
    float s0 = 0.f, s1 = 0.f, s2 = 0.f, s3 = 0.f;
    int t = 0;
    for (; t + 4 <= deg; t += 4) {
      int2 r0 = recs[beg + t + 0];
      int2 r1 = recs[beg + t + 1];
      int2 r2 = recs[beg + t + 2];
      int2 r3 = recs[beg + t + 3];
      uint2 q0 = *((const uint2*)(Y2B + (long long)r0.x * 32) + c);
      uint2 q1 = *((const uint2*)(Y2B + (long long)r1.x * 32) + c);
      uint2 q2 = *((const uint2*)(Y2B + (long long)r2.x * 32) + c);
      uint2 q3 = *((const uint2*)(Y2B + (long long)r3.x * 32) + c);
      s0 += bflo(q0.x) + bflo(q1.x) + bflo(q2.x) + bflo(q3.x);
      s1 += bfhi(q0.x) + bfhi(q1.x) + bfhi(q2.x) + bfhi(q3.x);
      s2 += bflo(q0.y) + bflo(q1.y) + bflo(q2.y) + bflo(q3.y);
      s3 += bfhi(q0.y) + bfhi(q1.y) + bfhi(q2.y) + bfhi(q3.y);
    }
    for (; t < deg; ++t) {
      int2 r = recs[beg + t];
      uint2 q = *((const uint2*)(Y2B + (long long)r.x * 32) + c);
      s0 += bflo(q.x); s1 += bfhi(q.x);
      s2 += bflo(q.y); s3 += bfhi(q.y);
    }
    float* sr = &sums[tp][th * 8 + g][c * 4];
    sr[0] = s0; sr[1] = s1; sr[2] = s2; sr[3] = s3;
  }
  __syncthreads();
  if (valid) {
    int m = lane & 15, quad = lane >> 4;
    int bf = flags[1];
    long long n0 = tile * 16;
    const unsigned short* f2 = F2 + (n0 + m) * 96 + quad * 8;
    short8x A[3];
#pragma unroll
    for (int cc = 0; cc < 3; ++cc) A[cc] = *(const short8x*)(f2 + cc * 32);
    short8x Bf[3];
#pragma unroll
    for (int cc = 0; cc < 3; ++cc)
      Bf[cc] = *(const short8x*)(PK + 12288 + ((cc * 2 + th) * 64 + lane) * 8);
    f32x4 acc;
    float fb = fb2s[th * 16 + m];
#pragma unroll
    for (int i = 0; i < 4; ++i) acc[i] = fb + sums[tp][quad * 4 + i][th * 16 + m];
#pragma unroll
    for (int cc = 0; cc < 3; ++cc)
      acc = __builtin_amdgcn_mfma_f32_16x16x32_bf16(A[cc], Bf[cc], acc, 0, 0, 0);
#pragma unroll
    for (int i = 0; i < 4; ++i) {
      long long idx = (n0 + quad * 4 + i) * 32 + th * 16 + m;
      if (bf) ((unsigned short*)out)[idx] = f2bf(acc[i]);
      else ((float*)out)[idx] = acc[i];
    }
  }
}

extern "C" void kernel_launch(void* const* d_in, const int* in_sizes, int n_in,
                              void* d_out, int out_size, void* d_ws, size_t ws_size,
                              hipStream_t stream) {
  const void* x = d_in[0];
  const void* ei = d_in[1];
  const void* ea = d_in[2];
  const void* W1_msg = d_in[3];
  const void* b1_msg = d_in[4];
  const void* W1_self = d_in[5];
  const void* b1_self = d_in[6];
  const void* gamma = d_in[7];
  const void* beta = d_in[8];
  const void* mean = d_in[9];
  const void* var = d_in[10];
  const void* W2_msg = d_in[11];
  const void* b2_msg = d_in[12];
  const void* W2_self = d_in[13];
  const void* b2_self = d_in[14];

  float* ws = (float*)d_ws;
  int* row_ptr = (int*)(ws + OFF_ROW);
  int2* recs = (int2*)(ws + OFF_RECS);
  int* flags = (int*)(ws + OFF_FLAGS);
  unsigned short* PK = (unsigned short*)(ws + OFF_PK);
  float* fb1s = ws + OFF_FB1S;
  float* fb2s = ws + OFF_FB2S;
  int2* binbuf = (int2*)(ws + OFF_F1);  // uses the old F1 region (F1 buffer eliminated)
  unsigned short* F2 = (unsigned short*)(ws + OFF_F2);
  unsigned short* Y2B = (unsigned short*)(ws + OFF_Y2B);
  int* bcur = (int*)(ws + OFF_BCUR);

  hipMemsetAsync(bcur, 0, NBK * sizeof(int), stream);
  hipLaunchKernelGGL(k_prepbin, dim3(BINBLK + PREPBLK), dim3(256), 0, stream, ei, x,
                     W1_msg, b1_msg, W1_self, b1_self, gamma, beta, mean, var, W2_msg,
                     b2_msg, W2_self, b2_self, flags, PK, fb1s, fb2s, bcur, binbuf);
  hipLaunchKernelGGL(k_place, dim3(NBK), dim3(1024), 0, stream, bcur, binbuf, row_ptr,
                     recs);

  int fblocks = (NT + 1) / 2;  // 1563 blocks x 4 waves = 6252 waves
  hipLaunchKernelGGL(k_gg1, dim3(fblocks), dim3(256), 0, stream, x, ea, row_ptr, recs,
                     flags, PK, fb1s, F2, Y2B);
  hipLaunchKernelGGL(k_gg2, dim3(fblocks), dim3(256), 0, stream, F2, PK, fb2s, Y2B,
                     row_ptr, recs, flags, d_out);
}